// Round 15
// baseline (305.361 us; speedup 1.0000x reference)
//
#include <hip/hip_runtime.h>
#include <hip/hip_bf16.h>
#include <math.h>

// ---------------- constants (problem-fixed shapes) ----------------
constexpr int Bn  = 4;      // batch
constexpr int Din = 192;    // d_inner
constexpr int Ll  = 4096;   // L = H*W
constexpr int Kk  = 4;      // scan directions
constexpr int Ns  = 16;     // d_state
constexpr int NCH = 128;    // scan chunks
constexpr int CLen= 32;     // chunk length
constexpr float EPSBN = 1e-5f;
constexpr float EPSLN = 1e-5f;

#define DEV __device__ __forceinline__

DEV float siluf_(float x){ return x / (1.f + __expf(-x)); }
DEV float softplusf_(float x){ return x > 15.f ? x : __logf(1.f + __expf(x)); }

// ---------------- K1: in_proj GEMM (nb*4096 x 96 @ 96 x 384^T) + split + silu(z) ----------------
__global__ __launch_bounds__(256) void k_inproj(const float* __restrict__ x,
                                                const float* __restrict__ w,
                                                float* __restrict__ xi_pre,
                                                float* __restrict__ zbuf){
  __shared__ __align__(16) float As[32][72];
  __shared__ __align__(16) float Bs[32][72];
  int t = threadIdx.x, tx = t & 15, ty = t >> 4;
  int m0 = blockIdx.x * 64, o0 = blockIdx.y * 64;
  float acc[4][4] = {};
  for (int k0 = 0; k0 < 96; k0 += 32){
    #pragma unroll
    for (int i = 0; i < 8; i++){ int e = t + i*256; int kk = e & 31, mm = e >> 5;
      As[kk][mm] = x[(size_t)(m0+mm)*96 + k0+kk]; }
    #pragma unroll
    for (int i = 0; i < 8; i++){ int e = t + i*256; int kk = e & 31, nn = e >> 5;
      Bs[kk][nn] = w[(size_t)(o0+nn)*96 + k0+kk]; }
    __syncthreads();
    #pragma unroll
    for (int kk = 0; kk < 32; kk++){
      float a[4], bb[4];
      #pragma unroll
      for (int i = 0; i < 4; i++) a[i]  = As[kk][tx + 16*i];
      #pragma unroll
      for (int j = 0; j < 4; j++) bb[j] = Bs[kk][ty + 16*j];
      #pragma unroll
      for (int i = 0; i < 4; i++)
        #pragma unroll
        for (int j = 0; j < 4; j++) acc[i][j] = fmaf(a[i], bb[j], acc[i][j]);
    }
    __syncthreads();
  }
  #pragma unroll
  for (int i = 0; i < 4; i++){
    int m = m0 + tx + 16*i; int b = m >> 12, l = m & 4095;
    #pragma unroll
    for (int j = 0; j < 4; j++){
      int o = o0 + ty + 16*j; float v = acc[i][j];
      if (o < Din) xi_pre[((size_t)b*Din + o)*Ll + l] = v;
      else         zbuf[((size_t)b*Din + (o-Din))*Ll + l] = siluf_(v);
    }
  }
}

// ---------------- K2: depthwise 3x3 conv + bias + silu; IN-PLACE xi, also emits xiT ----------------
__global__ __launch_bounds__(256) void k_dwconv(float* __restrict__ xi,
                                                const float* __restrict__ cw,
                                                const float* __restrict__ cb,
                                                float* __restrict__ xiT){
  __shared__ float pl[64][65];
  __shared__ float po[64][65];
  int g = blockIdx.x; int d = g % Din;
  int t = threadIdx.x;
  float* plane = xi + (size_t)g*Ll;
  #pragma unroll
  for (int i = 0; i < 16; i++){ int p = t + i*256; pl[p>>6][p&63] = plane[p]; }
  float w9[9];
  #pragma unroll
  for (int j = 0; j < 9; j++) w9[j] = cw[d*9 + j];
  float bias = cb[d];
  __syncthreads();
  float out[16];
  #pragma unroll
  for (int i = 0; i < 16; i++){
    int p = t + i*256; int h = p >> 6, wv = p & 63;
    float s = bias;
    #pragma unroll
    for (int r = 0; r < 3; r++){
      int hy = h + r - 1; if (hy < 0 || hy > 63) continue;
      #pragma unroll
      for (int c = 0; c < 3; c++){
        int wx = wv + c - 1; if (wx < 0 || wx > 63) continue;
        s = fmaf(pl[hy][wx], w9[r*3+c], s);
      }
    }
    out[i] = siluf_(s);
  }
  __syncthreads();
  #pragma unroll
  for (int i = 0; i < 16; i++){ int p = t + i*256; po[p>>6][p&63] = out[i]; plane[p] = out[i]; }
  __syncthreads();
  float* dxt = xiT + (size_t)g*Ll;
  #pragma unroll
  for (int i = 0; i < 16; i++){ int p = t + i*256; dxt[p] = po[p&63][p>>6]; }
}

// ---------------- K3: x_dbl = einsum('bkdl,kcd->bkcl') — r12 shape + register prefetch ----------------
__global__ __launch_bounds__(256) void k_xdbl(const float* __restrict__ xi,
                                              const float* __restrict__ xiT,
                                              const float* __restrict__ xpw,
                                              float* __restrict__ xdbl){
  __shared__ float us[24][132];
  __shared__ __align__(16) float wl[24][40];
  int g = blockIdx.x; int b = g >> 7; int k = (g >> 5) & 3; int lt = g & 31;
  int l0 = lt * 128; int t = threadIdx.x;
  int lw = t & 127; int cg = t >> 7;          // c-group 0/1 (c = cg*20 .. +19)
  const float* src = (k & 1) ? xiT : xi;
  bool rev = (k >= 2);
  if (t < 48){ wl[t >> 1][38 + (t & 1)] = 0.f; }   // pad cols, written once
  float acc[20];
  #pragma unroll
  for (int j = 0; j < 20; j++) acc[j] = 0.f;
  float upf[12]; float wpf[4];
  // prefetch chunk 0
  #pragma unroll
  for (int i = 0; i < 12; i++){ int e = t + i*256; int dd = e >> 7, ll = e & 127;
    int sp = rev ? (4095 - (l0 + ll)) : (l0 + ll);
    upf[i] = src[((size_t)b*Din + dd)*Ll + sp]; }
  #pragma unroll
  for (int i = 0; i < 4; i++){ int e = t + i*256;
    if (e < 912){ int dd = e % 24, c = e / 24; wpf[i] = xpw[(k*38 + c)*Din + dd]; } }
  for (int dc = 0; dc < 8; dc++){
    #pragma unroll
    for (int i = 0; i < 12; i++){ int e = t + i*256; us[e >> 7][e & 127] = upf[i]; }
    #pragma unroll
    for (int i = 0; i < 4; i++){ int e = t + i*256;
      if (e < 912){ wl[e % 24][e / 24] = wpf[i]; } }
    __syncthreads();
    if (dc < 7){
      int d0n = (dc + 1) * 24;
      #pragma unroll
      for (int i = 0; i < 12; i++){ int e = t + i*256; int dd = e >> 7, ll = e & 127;
        int sp = rev ? (4095 - (l0 + ll)) : (l0 + ll);
        upf[i] = src[((size_t)b*Din + d0n + dd)*Ll + sp]; }
      #pragma unroll
      for (int i = 0; i < 4; i++){ int e = t + i*256;
        if (e < 912){ int dd = e % 24, c = e / 24; wpf[i] = xpw[(k*38 + c)*Din + d0n + dd]; } }
    }
    #pragma unroll
    for (int dd = 0; dd < 24; dd++){
      float u = us[dd][lw];
      const float4* wp = (const float4*)&wl[dd][cg*20];
      #pragma unroll
      for (int q = 0; q < 5; q++){
        float4 w4 = wp[q];
        acc[q*4+0] = fmaf(u, w4.x, acc[q*4+0]);
        acc[q*4+1] = fmaf(u, w4.y, acc[q*4+1]);
        acc[q*4+2] = fmaf(u, w4.z, acc[q*4+2]);
        acc[q*4+3] = fmaf(u, w4.w, acc[q*4+3]);
      }
    }
    __syncthreads();
  }
  float* dst = xdbl + ((size_t)(b*Kk + k)*38)*Ll + l0 + lw;
  #pragma unroll
  for (int j = 0; j < 20; j++){
    int c = cg*20 + j;
    if (c < 38) dst[(size_t)c*Ll] = acc[j];
  }
}

// ---------------- K4: scan pass 1 — software-pipelined dt/exp prologue (4 x 8 steps) ----------------
__global__ __launch_bounds__(192) void k_scan1(const float* __restrict__ xi,
                                               const float* __restrict__ xiT,
                                               const float* __restrict__ xdbl,
                                               const float* __restrict__ dtw_g,
                                               const float* __restrict__ dtb_g,
                                               const float* __restrict__ Alog,
                                               float* __restrict__ hend,
                                               float* __restrict__ dtsum){
  __shared__ __align__(16) float bc[CLen][16];
  __shared__ __align__(16) float dr[CLen][8];
  __shared__ float us[192][CLen+1];
  int g = blockIdx.x;
  int b = g / (Kk*NCH); int k = (g / NCH) & 3; int ch = g % NCH;
  int l0 = ch * CLen;
  int t = threadIdx.x;             // t = d (0..191)
  const float* xb = xdbl + ((size_t)(b*Kk + k)*38)*Ll;
  for (int e = t; e < CLen*16; e += 192){ int n = e / CLen, ll = e % CLen;
    bc[ll][n] = xb[(6 + n)*Ll + l0 + ll]; }
  for (int e = t; e < CLen*6; e += 192){ int r = e / CLen, ll = e % CLen;
    dr[ll][r] = xb[r*Ll + l0 + ll]; }
  const float* ubase = ((k & 1) ? xiT : xi) + (size_t)b*Din*Ll;
  bool rev = (k >= 2);
  for (int e = t; e < 192*CLen; e += 192){
    int dd = e >> 5, ll = e & 31;
    int sp = rev ? (Ll-1 - l0 - ll) : (l0 + ll);
    us[dd][ll] = ubase[(size_t)dd*Ll + sp];
  }
  int d = t; int kd = k*Din + d;
  float dtw[6];
  #pragma unroll
  for (int r = 0; r < 6; r++) dtw[r] = dtw_g[kd*6 + r];
  float dtb = dtb_g[kd];
  float Ar[16];
  #pragma unroll
  for (int n = 0; n < 16; n++) Ar[n] = -__expf(Alog[kd*16 + n]);
  bool ok = true;
  #pragma unroll
  for (int n = 1; n < 16; n++)
    ok = ok && (fabsf(Ar[n] - (n+1)*Ar[0]) <= 1e-4f*fabsf(Ar[n]) + 1e-30f);
  float h[16];
  #pragma unroll
  for (int n = 0; n < 16; n++) h[n] = 0.f;
  float dts_acc = 0.f;
  __syncthreads();
  if (ok){
    for (int c4 = 0; c4 < 4; c4++){
      float dts[8], e1s[8];
      #pragma unroll
      for (int j = 0; j < 8; j++){
        int ll = c4*8 + j;
        float4 q0 = *(const float4*)&dr[ll][0];
        float4 q1 = *(const float4*)&dr[ll][4];
        float xv = dtb;
        xv = fmaf(dtw[0], q0.x, xv); xv = fmaf(dtw[1], q0.y, xv); xv = fmaf(dtw[2], q0.z, xv);
        xv = fmaf(dtw[3], q0.w, xv); xv = fmaf(dtw[4], q1.x, xv); xv = fmaf(dtw[5], q1.y, xv);
        dts[j] = softplusf_(xv);
        e1s[j] = __expf(dts[j] * Ar[0]);
      }
      #pragma unroll
      for (int j = 0; j < 8; j++){
        int ll = c4*8 + j;
        float dt = dts[j];
        float u = us[d][ll];
        float dtu = dt * u;
        float e1 = e1s[j];
        float e2=e1*e1, e4=e2*e2, e8=e4*e4;
        float dA[16];
        dA[0]=e1; dA[1]=e2; dA[2]=e2*e1; dA[3]=e4; dA[4]=e4*e1; dA[5]=e4*e2; dA[6]=e4*e2*e1;
        dA[7]=e8; dA[8]=e8*e1; dA[9]=e8*e2; dA[10]=e8*e2*e1; dA[11]=e8*e4; dA[12]=e8*e4*e1;
        dA[13]=e8*e4*e2; dA[14]=e8*e4*e2*e1; dA[15]=e8*e8;
        float4 B0 = *(const float4*)&bc[ll][0];
        float4 B1 = *(const float4*)&bc[ll][4];
        float4 B2 = *(const float4*)&bc[ll][8];
        float4 B3 = *(const float4*)&bc[ll][12];
        float Bv[16] = {B0.x,B0.y,B0.z,B0.w,B1.x,B1.y,B1.z,B1.w,
                        B2.x,B2.y,B2.z,B2.w,B3.x,B3.y,B3.z,B3.w};
        #pragma unroll
        for (int n = 0; n < 16; n++) h[n] = fmaf(h[n], dA[n], dtu * Bv[n]);
        dts_acc += dt;
      }
    }
  } else {
    for (int ll = 0; ll < CLen; ll++){
      float4 q0 = *(const float4*)&dr[ll][0];
      float4 q1 = *(const float4*)&dr[ll][4];
      float xv = dtb;
      xv = fmaf(dtw[0], q0.x, xv); xv = fmaf(dtw[1], q0.y, xv); xv = fmaf(dtw[2], q0.z, xv);
      xv = fmaf(dtw[3], q0.w, xv); xv = fmaf(dtw[4], q1.x, xv); xv = fmaf(dtw[5], q1.y, xv);
      float dt = softplusf_(xv);
      float u = us[d][ll];
      float dtu = dt * u;
      float4 B0 = *(const float4*)&bc[ll][0];
      float4 B1 = *(const float4*)&bc[ll][4];
      float4 B2 = *(const float4*)&bc[ll][8];
      float4 B3 = *(const float4*)&bc[ll][12];
      float Bv[16] = {B0.x,B0.y,B0.z,B0.w,B1.x,B1.y,B1.z,B1.w,
                      B2.x,B2.y,B2.z,B2.w,B3.x,B3.y,B3.z,B3.w};
      #pragma unroll
      for (int n = 0; n < 16; n++){
        float dA = __expf(dt * Ar[n]);
        h[n] = fmaf(h[n], dA, dtu * Bv[n]);
      }
      dts_acc += dt;
    }
  }
  float4* hp = (float4*)&hend[(((size_t)(b*Kk + k)*NCH + ch)*Din + d)*16];
  #pragma unroll
  for (int q = 0; q < 4; q++){
    float4 v; v.x = h[q*4]; v.y = h[q*4+1]; v.z = h[q*4+2]; v.w = h[q*4+3];
    hp[q] = v;
  }
  dtsum[((size_t)(b*Kk + k)*NCH + ch)*Din + d] = dts_acc;
}

// ---------------- K5: serial combine across chunks, IN-PLACE hend -> hin ----------------
__global__ __launch_bounds__(256) void k_combine(const float* __restrict__ Alog,
                                                 const float* __restrict__ dtsum,
                                                 float* __restrict__ hbuf){
  __shared__ float ds_s[NCH][17];
  int blk = blockIdx.x;
  int bk = blk / 12; int d0 = (blk % 12) * 16;   // Din*Ns/256 = 12
  int k = bk & 3;
  int t = threadIdx.x; int n = t & 15; int dd = t >> 4;  // dd 0..15
  int d = d0 + dd;
  for (int e = t; e < NCH*16; e += 256){ int c = e >> 4, di = e & 15;
    ds_s[c][di] = dtsum[(size_t)bk*NCH*Din + (size_t)c*Din + d0 + di]; }
  float A = -__expf(Alog[(k*Din + d)*16 + n]);
  __syncthreads();
  float h = 0.f;
  size_t base = ((size_t)bk*NCH*Din + d)*16 + n;       // + c*Din*16
  #pragma unroll 4
  for (int c = 0; c < NCH; c++){
    size_t idx = base + (size_t)c*(Din*16);
    float tmp = hbuf[idx];
    hbuf[idx] = h;                                     // prefix state (hin)
    h = fmaf(h, __expf(A * ds_s[c][dd]), tmp);
  }
}

// ---------------- K6: scan pass 2 — software-pipelined; y via LDS -> coalesced store ----------------
__global__ __launch_bounds__(192) void k_scany(const float* __restrict__ xi,
                                               const float* __restrict__ xiT,
                                               const float* __restrict__ xdbl,
                                               const float* __restrict__ dtw_g,
                                               const float* __restrict__ dtb_g,
                                               const float* __restrict__ Alog,
                                               const float* __restrict__ Ds_g,
                                               const float* __restrict__ hin,
                                               float* __restrict__ y0,
                                               float* __restrict__ y1,
                                               float* __restrict__ y2p,
                                               float* __restrict__ y3){
  // bc layout per ll: [0..15]=B, [16..31]=C, [32..37]=dt-raw (38,39 pad)
  __shared__ __align__(16) float bc[CLen][40];
  __shared__ float us[192][CLen+1];      // u on input; y on output (slot reused per step)
  int g = blockIdx.x;
  int b = g / (Kk*NCH); int k = (g / NCH) & 3; int ch = g % NCH;
  int l0 = ch * CLen; int t = threadIdx.x;
  const float* xb = xdbl + ((size_t)(b*Kk + k)*38)*Ll;
  for (int e = t; e < CLen*38; e += 192){
    int c = e / CLen, ll = e % CLen;
    int cp = (c < 6) ? (32 + c) : (c - 6);
    bc[ll][cp] = xb[c*Ll + l0 + ll];
  }
  const float* ubase = ((k & 1) ? xiT : xi) + (size_t)b*Din*Ll;
  bool rev = (k >= 2);
  for (int e = t; e < 192*CLen; e += 192){
    int dd = e >> 5, ll = e & 31;
    int sp = rev ? (Ll-1 - l0 - ll) : (l0 + ll);
    us[dd][ll] = ubase[(size_t)dd*Ll + sp];
  }
  int d = t; int kd = k*Din + d;
  float dtw[6];
  #pragma unroll
  for (int r = 0; r < 6; r++) dtw[r] = dtw_g[kd*6 + r];
  float dtb = dtb_g[kd];
  float Ar[16];
  #pragma unroll
  for (int n = 0; n < 16; n++) Ar[n] = -__expf(Alog[kd*16 + n]);
  bool ok = true;
  #pragma unroll
  for (int n = 1; n < 16; n++)
    ok = ok && (fabsf(Ar[n] - (n+1)*Ar[0]) <= 1e-4f*fabsf(Ar[n]) + 1e-30f);
  float Dk = Ds_g[kd];
  float h[16];
  {
    const float4* hp = (const float4*)&hin[(((size_t)(b*Kk + k)*NCH + ch)*Din + d)*16];
    #pragma unroll
    for (int q = 0; q < 4; q++){ float4 v = hp[q];
      h[q*4] = v.x; h[q*4+1] = v.y; h[q*4+2] = v.z; h[q*4+3] = v.w; }
  }
  __syncthreads();
  if (ok){
    for (int c4 = 0; c4 < 4; c4++){
      float dts[8], e1s[8];
      #pragma unroll
      for (int j = 0; j < 8; j++){
        int ll = c4*8 + j;
        float4 q0 = *(const float4*)&bc[ll][32];
        float4 q1 = *(const float4*)&bc[ll][36];
        float xv = dtb;
        xv = fmaf(dtw[0], q0.x, xv); xv = fmaf(dtw[1], q0.y, xv); xv = fmaf(dtw[2], q0.z, xv);
        xv = fmaf(dtw[3], q0.w, xv); xv = fmaf(dtw[4], q1.x, xv); xv = fmaf(dtw[5], q1.y, xv);
        dts[j] = softplusf_(xv);
        e1s[j] = __expf(dts[j] * Ar[0]);
      }
      #pragma unroll
      for (int j = 0; j < 8; j++){
        int ll = c4*8 + j;
        float dt = dts[j];
        float u = us[d][ll];
        float dtu = dt * u;
        float e1 = e1s[j];
        float e2=e1*e1, e4=e2*e2, e8=e4*e4;
        float dA[16];
        dA[0]=e1; dA[1]=e2; dA[2]=e2*e1; dA[3]=e4; dA[4]=e4*e1; dA[5]=e4*e2; dA[6]=e4*e2*e1;
        dA[7]=e8; dA[8]=e8*e1; dA[9]=e8*e2; dA[10]=e8*e2*e1; dA[11]=e8*e4; dA[12]=e8*e4*e1;
        dA[13]=e8*e4*e2; dA[14]=e8*e4*e2*e1; dA[15]=e8*e8;
        float4 B0 = *(const float4*)&bc[ll][0];
        float4 B1 = *(const float4*)&bc[ll][4];
        float4 B2 = *(const float4*)&bc[ll][8];
        float4 B3 = *(const float4*)&bc[ll][12];
        float Bv[16] = {B0.x,B0.y,B0.z,B0.w,B1.x,B1.y,B1.z,B1.w,
                        B2.x,B2.y,B2.z,B2.w,B3.x,B3.y,B3.z,B3.w};
        #pragma unroll
        for (int n = 0; n < 16; n++) h[n] = fmaf(h[n], dA[n], dtu * Bv[n]);
        float4 C0 = *(const float4*)&bc[ll][16];
        float4 C1 = *(const float4*)&bc[ll][20];
        float4 C2 = *(const float4*)&bc[ll][24];
        float4 C3 = *(const float4*)&bc[ll][28];
        float Cv[16] = {C0.x,C0.y,C0.z,C0.w,C1.x,C1.y,C1.z,C1.w,
                        C2.x,C2.y,C2.z,C2.w,C3.x,C3.y,C3.z,C3.w};
        float y = 0.f;
        #pragma unroll
        for (int n = 0; n < 16; n++) y = fmaf(h[n], Cv[n], y);
        y = fmaf(Dk, u, y);
        us[d][ll] = y;                      // reuse LDS slot (u consumed this step)
      }
    }
  } else {
    for (int ll = 0; ll < CLen; ll++){
      float4 q0 = *(const float4*)&bc[ll][32];
      float4 q1 = *(const float4*)&bc[ll][36];
      float xv = dtb;
      xv = fmaf(dtw[0], q0.x, xv); xv = fmaf(dtw[1], q0.y, xv); xv = fmaf(dtw[2], q0.z, xv);
      xv = fmaf(dtw[3], q0.w, xv); xv = fmaf(dtw[4], q1.x, xv); xv = fmaf(dtw[5], q1.y, xv);
      float dt = softplusf_(xv);
      float u = us[d][ll];
      float dtu = dt * u;
      float4 B0 = *(const float4*)&bc[ll][0];
      float4 B1 = *(const float4*)&bc[ll][4];
      float4 B2 = *(const float4*)&bc[ll][8];
      float4 B3 = *(const float4*)&bc[ll][12];
      float Bv[16] = {B0.x,B0.y,B0.z,B0.w,B1.x,B1.y,B1.z,B1.w,
                      B2.x,B2.y,B2.z,B2.w,B3.x,B3.y,B3.z,B3.w};
      #pragma unroll
      for (int n = 0; n < 16; n++){
        float dA = __expf(dt * Ar[n]);
        h[n] = fmaf(h[n], dA, dtu * Bv[n]);
      }
      float4 C0 = *(const float4*)&bc[ll][16];
      float4 C1 = *(const float4*)&bc[ll][20];
      float4 C2 = *(const float4*)&bc[ll][24];
      float4 C3 = *(const float4*)&bc[ll][28];
      float Cv[16] = {C0.x,C0.y,C0.z,C0.w,C1.x,C1.y,C1.z,C1.w,
                      C2.x,C2.y,C2.z,C2.w,C3.x,C3.y,C3.z,C3.w};
      float y = 0.f;
      #pragma unroll
      for (int n = 0; n < 16; n++) y = fmaf(h[n], Cv[n], y);
      y = fmaf(Dk, u, y);
      us[d][ll] = y;
    }
  }
  __syncthreads();
  // coalesced write-out: mirrors the staging loop (32-lane groups, 128B contiguous)
  float* yplane = (k == 0 ? y0 : k == 1 ? y1 : k == 2 ? y2p : y3) + (size_t)b*Din*Ll;
  for (int e = t; e < 192*CLen; e += 192){
    int dd = e >> 5, ll = e & 31;
    int sp = rev ? (Ll-1 - l0 - ll) : (l0 + ll);
    yplane[(size_t)dd*Ll + sp] = us[dd][ll];
  }
}

// ---------------- K7: merge y0 += y2p + T(y1 + y3), in place ----------------
__global__ __launch_bounds__(256) void k_merge(float* __restrict__ y0,
                                               const float* __restrict__ y1,
                                               const float* __restrict__ y2p,
                                               const float* __restrict__ y3){
  __shared__ float pl[64][65];
  int g = blockIdx.x;
  int t = threadIdx.x;
  const float* s1 = y1 + (size_t)g*Ll;
  const float* s3 = y3 + (size_t)g*Ll;
  const float* s2 = y2p + (size_t)g*Ll;
  float* dst = y0 + (size_t)g*Ll;
  #pragma unroll
  for (int i = 0; i < 16; i++){ int p = t + i*256; pl[p>>6][p&63] = s1[p] + s3[p]; }
  __syncthreads();
  #pragma unroll
  for (int i = 0; i < 16; i++){ int p = t + i*256; dst[p] += s2[p] + pl[p&63][p>>6]; }
}

// ---------------- K8: channel LayerNorm + gate (y * silu_z) ----------------
__global__ __launch_bounds__(256) void k_ln(const float* __restrict__ ycf,
                                            const float* __restrict__ zbuf,
                                            const float* __restrict__ gam,
                                            const float* __restrict__ bet,
                                            float* __restrict__ gbuf){
  __shared__ float sred[2][4][64];
  __shared__ float smu[64], srs[64];
  int g = blockIdx.x; int b = g >> 6; int l0 = (g & 63) * 64;
  int t = threadIdx.x; int lw = t & 63; int dg = t >> 6;
  size_t pbase = ((size_t)b*Din + dg*48)*Ll + l0 + lw;
  float sum = 0.f, ss = 0.f;
  for (int dd = 0; dd < 48; dd++){
    float v = ycf[pbase + (size_t)dd*Ll]; sum += v; ss = fmaf(v, v, ss);
  }
  sred[0][dg][lw] = sum; sred[1][dg][lw] = ss;
  __syncthreads();
  if (t < 64){
    float s = sred[0][0][t] + sred[0][1][t] + sred[0][2][t] + sred[0][3][t];
    float q = sred[1][0][t] + sred[1][1][t] + sred[1][2][t] + sred[1][3][t];
    float mu = s * (1.f/192.f);
    float var = q * (1.f/192.f) - mu*mu;
    smu[t] = mu; srs[t] = rsqrtf(var + EPSLN);
  }
  __syncthreads();
  float mu = smu[lw], rs = srs[lw];
  for (int dd = 0; dd < 48; dd++){
    int d = dg*48 + dd;
    float v = ycf[pbase + (size_t)dd*Ll];
    float vn = (v - mu)*rs*gam[d] + bet[d];
    float zz = zbuf[((size_t)b*Din + d)*Ll + l0 + lw];
    gbuf[((size_t)b*Din + d)*Ll + l0 + lw] = vn * zz;
  }
}

// ---------------- K9: 3 dilated depthwise convs + BN + ReLU -> cat ----------------
__global__ __launch_bounds__(256) void k_branch(const float* __restrict__ gbuf,
                                                const float* __restrict__ brw,
                                                const float* __restrict__ brg,
                                                const float* __restrict__ brb,
                                                float* __restrict__ cat){
  __shared__ float pl[64][65];
  int g = blockIdx.x; int b = g / Din, d = g % Din;
  int t = threadIdx.x;
  const float* src = gbuf + (size_t)g*Ll;
  #pragma unroll
  for (int i = 0; i < 16; i++){ int p = t + i*256; pl[p>>6][p&63] = src[p]; }
  float w[3][9]; float sc[3], bi[3];
  const float inv = rsqrtf(1.f + EPSBN);
  #pragma unroll
  for (int ib = 0; ib < 3; ib++){
    #pragma unroll
    for (int j = 0; j < 9; j++) w[ib][j] = brw[(ib*Din + d)*9 + j];
    sc[ib] = brg[ib*Din + d] * inv; bi[ib] = brb[ib*Din + d];
  }
  __syncthreads();
  const int dils[3] = {1, 2, 4};
  #pragma unroll
  for (int i = 0; i < 16; i++){
    int p = t + i*256; int h = p >> 6, wv = p & 63;
    #pragma unroll
    for (int ib = 0; ib < 3; ib++){
      int dil = dils[ib];
      float s = 0.f;
      #pragma unroll
      for (int r = 0; r < 3; r++){
        int hy = h + (r-1)*dil; if (hy < 0 || hy > 63) continue;
        #pragma unroll
        for (int c = 0; c < 3; c++){
          int wx = wv + (c-1)*dil; if (wx < 0 || wx > 63) continue;
          s = fmaf(pl[hy][wx], w[ib][r*3+c], s);
        }
      }
      s = s*sc[ib] + bi[ib];
      s = s > 0.f ? s : 0.f;
      cat[((size_t)b*576 + ib*Din + d)*Ll + p] = s;
    }
  }
}

// ---------------- K10: fuse 1x1 GEMM, M=64 N=96 K=32, 512 threads; cat read once ----------------
__global__ __launch_bounds__(512) void k_fuse(const float* __restrict__ cat,
                                              const float* __restrict__ fw,
                                              const float* __restrict__ fg,
                                              const float* __restrict__ fb,
                                              float* __restrict__ out){
  __shared__ float As[32][65];   // [k][m]  odd stride -> conflict-free
  __shared__ float Bs[32][97];   // [k][n]  odd stride -> conflict-free
  int t = threadIdx.x;
  int tx = t & 31, ty = t >> 5;              // tx -> n (0..31), ty -> m (0..15)
  int m0 = blockIdx.x * 64; int b = m0 >> 12; int l0 = m0 & 4095;
  float acc[4][3] = {};
  for (int k0 = 0; k0 < 576; k0 += 32){
    #pragma unroll
    for (int i = 0; i < 4; i++){ int e = t + i*512; int mm = e & 63, kk = e >> 6;
      As[kk][mm] = cat[((size_t)b*576 + k0 + kk)*Ll + l0 + mm]; }
    #pragma unroll
    for (int i = 0; i < 6; i++){ int e = t + i*512; int kk = e & 31, oo = e >> 5;
      Bs[kk][oo] = fw[(size_t)oo*576 + k0 + kk]; }
    __syncthreads();
    #pragma unroll
    for (int kk = 0; kk < 32; kk++){
      float a[4], bb[3];
      #pragma unroll
      for (int i = 0; i < 4; i++) a[i] = As[kk][ty + 16*i];
      #pragma unroll
      for (int j = 0; j < 3; j++) bb[j] = Bs[kk][tx + 32*j];
      #pragma unroll
      for (int i = 0; i < 4; i++)
        #pragma unroll
        for (int j = 0; j < 3; j++) acc[i][j] = fmaf(a[i], bb[j], acc[i][j]);
    }
    __syncthreads();
  }
  const float inv = rsqrtf(1.f + EPSBN);
  #pragma unroll
  for (int j = 0; j < 3; j++){
    int o = tx + 32*j;
    float sc = fg[o]*inv, bi = fb[o];
    #pragma unroll
    for (int i = 0; i < 4; i++){
      int m = m0 + ty + 16*i;
      float v = acc[i][j]*sc + bi;
      v = v > 0.f ? v : 0.f;
      out[(size_t)m*96 + o] = v;
    }
  }
}

// ---------------- diagnostic sentinel: ws too small even for G=1 ----------------
__global__ void k_sentinel(float* out, int n){
  int i = blockIdx.x*256 + threadIdx.x;
  if (i < n) out[i] = 1.5f;
}

// ---------------- launch ----------------
extern "C" void kernel_launch(void* const* d_in, const int* in_sizes, int n_in,
                              void* d_out, int out_size, void* d_ws, size_t ws_size,
                              hipStream_t stream){
  const float* x    = (const float*)d_in[0];
  const float* ipw  = (const float*)d_in[1];
  const float* cw   = (const float*)d_in[2];
  const float* cb   = (const float*)d_in[3];
  const float* xpw  = (const float*)d_in[4];
  const float* dtw  = (const float*)d_in[5];
  const float* dtb  = (const float*)d_in[6];
  const float* Alog = (const float*)d_in[7];
  const float* Ds   = (const float*)d_in[8];
  const float* ong  = (const float*)d_in[9];
  const float* onb  = (const float*)d_in[10];
  const float* brw  = (const float*)d_in[11];
  const float* brg  = (const float*)d_in[12];
  const float* brb  = (const float*)d_in[13];
  const float* fw   = (const float*)d_in[14];
  const float* fg   = (const float*)d_in[15];
  const float* fb   = (const float*)d_in[16];
  float* out = (float*)d_out;          // reference output dtype = float32

  // per-batch float counts
  const size_t P1     = (size_t)Din*Ll;        //   786,432 (one plane)
  const size_t S_xdbl = (size_t)Kk*38*Ll;      //   622,592
  const size_t S_h    = (size_t)Kk*NCH*Din*Ns; // 1,572,864
  const size_t S_dts  = (size_t)Kk*NCH*Din;    //    98,304
  const size_t perb   = 7*P1 + S_xdbl + S_h + S_dts;  // 7,798,784 floats = 31.2 MB

  int G = 4;
  if (ws_size < 4*perb*sizeof(float)) G = 2;
  if (ws_size < 2*perb*sizeof(float)) G = 1;
  if (ws_size < 1*perb*sizeof(float)){
    k_sentinel<<<(out_size + 255)/256, 256, 0, stream>>>(out, out_size);
    return;
  }

  float* wsf = (float*)d_ws;
  for (int b0 = 0; b0 < Bn; b0 += G){
    int nb = (Bn - b0 < G) ? (Bn - b0) : G;
    size_t nbP = (size_t)nb*P1;
    float* zbuf  = wsf;                 // [nbP]  plane 0   (cat overlays planes 0-2)
    float* y0    = zbuf + nbP;          // [nbP]  plane 1
    float* y1    = y0   + nbP;          // [nbP]  plane 2
    float* y2p   = y1   + nbP;          // [nbP]  plane 3
    float* y3    = y2p  + nbP;          // [nbP]  plane 4
    float* xi    = y3   + nbP;          // [nbP]  plane 5 (xi_pre -> xi in place; later gbuf)
    float* xiT   = xi   + nbP;          // [nbP]  plane 6
    float* xdbl  = xiT  + nbP;          // [nb*S_xdbl]
    float* hbuf  = xdbl + (size_t)nb*S_xdbl;  // [nb*S_h] (hend -> hin in place)
    float* dtsum = hbuf + (size_t)nb*S_h;     // [nb*S_dts]
    float* cat   = wsf;                 // [3*nbP] == nb*576*Ll exactly (planes 0-2)
    float* gbuf  = xi;

    const float* xg = x + (size_t)b0*Ll*96;
    float* outg = out + (size_t)b0*Ll*96;

    k_inproj <<<dim3(nb*64, 6), 256, 0, stream>>>(xg, ipw, xi, zbuf);
    k_dwconv <<<nb*Din, 256, 0, stream>>>(xi, cw, cb, xiT);
    k_xdbl   <<<nb*128, 256, 0, stream>>>(xi, xiT, xpw, xdbl);
    k_scan1  <<<nb*Kk*NCH, 192, 0, stream>>>(xi, xiT, xdbl, dtw, dtb, Alog, hbuf, dtsum);
    k_combine<<<nb*48, 256, 0, stream>>>(Alog, dtsum, hbuf);
    k_scany  <<<nb*Kk*NCH, 192, 0, stream>>>(xi, xiT, xdbl, dtw, dtb, Alog, Ds, hbuf,
                                             y0, y1, y2p, y3);
    k_merge  <<<nb*Din, 256, 0, stream>>>(y0, y1, y2p, y3);
    k_ln     <<<nb*64, 256, 0, stream>>>(y0, zbuf, ong, onb, gbuf);
    k_branch <<<nb*Din, 256, 0, stream>>>(gbuf, brw, brg, brb, cat);
    k_fuse   <<<nb*64, 512, 0, stream>>>(cat, fw, fg, fb, outg);
  }
}

// Round 16
// 268.308 us; speedup vs baseline: 1.1381x; 1.1381x over previous
//
#include <hip/hip_runtime.h>
#include <hip/hip_bf16.h>
#include <math.h>

// ---------------- constants (problem-fixed shapes) ----------------
constexpr int Bn  = 4;      // batch
constexpr int Din = 192;    // d_inner
constexpr int Ll  = 4096;   // L = H*W
constexpr int Kk  = 4;      // scan directions
constexpr int Ns  = 16;     // d_state
constexpr int NCH = 128;    // scan chunks
constexpr int CLen= 32;     // chunk length
constexpr float EPSBN = 1e-5f;
constexpr float EPSLN = 1e-5f;

#define DEV __device__ __forceinline__

DEV float siluf_(float x){ return x / (1.f + __expf(-x)); }
DEV float softplusf_(float x){ return x > 15.f ? x : __logf(1.f + __expf(x)); }

// ---------------- K1: in_proj GEMM (nb*4096 x 96 @ 96 x 384^T) + split + silu(z) ----------------
__global__ __launch_bounds__(256) void k_inproj(const float* __restrict__ x,
                                                const float* __restrict__ w,
                                                float* __restrict__ xi_pre,
                                                float* __restrict__ zbuf){
  __shared__ __align__(16) float As[32][72];
  __shared__ __align__(16) float Bs[32][72];
  int t = threadIdx.x, tx = t & 15, ty = t >> 4;
  int m0 = blockIdx.x * 64, o0 = blockIdx.y * 64;
  float acc[4][4] = {};
  for (int k0 = 0; k0 < 96; k0 += 32){
    #pragma unroll
    for (int i = 0; i < 8; i++){ int e = t + i*256; int kk = e & 31, mm = e >> 5;
      As[kk][mm] = x[(size_t)(m0+mm)*96 + k0+kk]; }
    #pragma unroll
    for (int i = 0; i < 8; i++){ int e = t + i*256; int kk = e & 31, nn = e >> 5;
      Bs[kk][nn] = w[(size_t)(o0+nn)*96 + k0+kk]; }
    __syncthreads();
    #pragma unroll
    for (int kk = 0; kk < 32; kk++){
      float a[4], bb[4];
      #pragma unroll
      for (int i = 0; i < 4; i++) a[i]  = As[kk][tx + 16*i];
      #pragma unroll
      for (int j = 0; j < 4; j++) bb[j] = Bs[kk][ty + 16*j];
      #pragma unroll
      for (int i = 0; i < 4; i++)
        #pragma unroll
        for (int j = 0; j < 4; j++) acc[i][j] = fmaf(a[i], bb[j], acc[i][j]);
    }
    __syncthreads();
  }
  #pragma unroll
  for (int i = 0; i < 4; i++){
    int m = m0 + tx + 16*i; int b = m >> 12, l = m & 4095;
    #pragma unroll
    for (int j = 0; j < 4; j++){
      int o = o0 + ty + 16*j; float v = acc[i][j];
      if (o < Din) xi_pre[((size_t)b*Din + o)*Ll + l] = v;
      else         zbuf[((size_t)b*Din + (o-Din))*Ll + l] = siluf_(v);
    }
  }
}

// ---------------- K2: depthwise 3x3 conv + bias + silu; IN-PLACE xi, also emits xiT ----------------
__global__ __launch_bounds__(256) void k_dwconv(float* __restrict__ xi,
                                                const float* __restrict__ cw,
                                                const float* __restrict__ cb,
                                                float* __restrict__ xiT){
  __shared__ float pl[64][65];
  __shared__ float po[64][65];
  int g = blockIdx.x; int d = g % Din;
  int t = threadIdx.x;
  float* plane = xi + (size_t)g*Ll;
  #pragma unroll
  for (int i = 0; i < 16; i++){ int p = t + i*256; pl[p>>6][p&63] = plane[p]; }
  float w9[9];
  #pragma unroll
  for (int j = 0; j < 9; j++) w9[j] = cw[d*9 + j];
  float bias = cb[d];
  __syncthreads();
  float out[16];
  #pragma unroll
  for (int i = 0; i < 16; i++){
    int p = t + i*256; int h = p >> 6, wv = p & 63;
    float s = bias;
    #pragma unroll
    for (int r = 0; r < 3; r++){
      int hy = h + r - 1; if (hy < 0 || hy > 63) continue;
      #pragma unroll
      for (int c = 0; c < 3; c++){
        int wx = wv + c - 1; if (wx < 0 || wx > 63) continue;
        s = fmaf(pl[hy][wx], w9[r*3+c], s);
      }
    }
    out[i] = siluf_(s);
  }
  __syncthreads();
  #pragma unroll
  for (int i = 0; i < 16; i++){ int p = t + i*256; po[p>>6][p&63] = out[i]; plane[p] = out[i]; }
  __syncthreads();
  float* dxt = xiT + (size_t)g*Ll;
  #pragma unroll
  for (int i = 0; i < 16; i++){ int p = t + i*256; dxt[p] = po[p&63][p>>6]; }
}

// ---------------- K3: x_dbl = einsum('bkdl,kcd->bkcl') — r12 shape + register prefetch ----------------
__global__ __launch_bounds__(256) void k_xdbl(const float* __restrict__ xi,
                                              const float* __restrict__ xiT,
                                              const float* __restrict__ xpw,
                                              float* __restrict__ xdbl){
  __shared__ float us[24][132];
  __shared__ __align__(16) float wl[24][40];
  int g = blockIdx.x; int b = g >> 7; int k = (g >> 5) & 3; int lt = g & 31;
  int l0 = lt * 128; int t = threadIdx.x;
  int lw = t & 127; int cg = t >> 7;          // c-group 0/1 (c = cg*20 .. +19)
  const float* src = (k & 1) ? xiT : xi;
  bool rev = (k >= 2);
  if (t < 48){ wl[t >> 1][38 + (t & 1)] = 0.f; }   // pad cols, written once
  float acc[20];
  #pragma unroll
  for (int j = 0; j < 20; j++) acc[j] = 0.f;
  float upf[12]; float wpf[4];
  // prefetch chunk 0
  #pragma unroll
  for (int i = 0; i < 12; i++){ int e = t + i*256; int dd = e >> 7, ll = e & 127;
    int sp = rev ? (4095 - (l0 + ll)) : (l0 + ll);
    upf[i] = src[((size_t)b*Din + dd)*Ll + sp]; }
  #pragma unroll
  for (int i = 0; i < 4; i++){ int e = t + i*256;
    if (e < 912){ int dd = e % 24, c = e / 24; wpf[i] = xpw[(k*38 + c)*Din + dd]; } }
  for (int dc = 0; dc < 8; dc++){
    #pragma unroll
    for (int i = 0; i < 12; i++){ int e = t + i*256; us[e >> 7][e & 127] = upf[i]; }
    #pragma unroll
    for (int i = 0; i < 4; i++){ int e = t + i*256;
      if (e < 912){ wl[e % 24][e / 24] = wpf[i]; } }
    __syncthreads();
    if (dc < 7){
      int d0n = (dc + 1) * 24;
      #pragma unroll
      for (int i = 0; i < 12; i++){ int e = t + i*256; int dd = e >> 7, ll = e & 127;
        int sp = rev ? (4095 - (l0 + ll)) : (l0 + ll);
        upf[i] = src[((size_t)b*Din + d0n + dd)*Ll + sp]; }
      #pragma unroll
      for (int i = 0; i < 4; i++){ int e = t + i*256;
        if (e < 912){ int dd = e % 24, c = e / 24; wpf[i] = xpw[(k*38 + c)*Din + d0n + dd]; } }
    }
    #pragma unroll
    for (int dd = 0; dd < 24; dd++){
      float u = us[dd][lw];
      const float4* wp = (const float4*)&wl[dd][cg*20];
      #pragma unroll
      for (int q = 0; q < 5; q++){
        float4 w4 = wp[q];
        acc[q*4+0] = fmaf(u, w4.x, acc[q*4+0]);
        acc[q*4+1] = fmaf(u, w4.y, acc[q*4+1]);
        acc[q*4+2] = fmaf(u, w4.z, acc[q*4+2]);
        acc[q*4+3] = fmaf(u, w4.w, acc[q*4+3]);
      }
    }
    __syncthreads();
  }
  float* dst = xdbl + ((size_t)(b*Kk + k)*38)*Ll + l0 + lw;
  #pragma unroll
  for (int j = 0; j < 20; j++){
    int c = cg*20 + j;
    if (c < 38) dst[(size_t)c*Ll] = acc[j];
  }
}

// ---------------- K4: scan pass 1 — per-chunk local end state + sum(dt)  (round-14 form) ----------------
__global__ __launch_bounds__(192) void k_scan1(const float* __restrict__ xi,
                                               const float* __restrict__ xiT,
                                               const float* __restrict__ xdbl,
                                               const float* __restrict__ dtw_g,
                                               const float* __restrict__ dtb_g,
                                               const float* __restrict__ Alog,
                                               float* __restrict__ hend,
                                               float* __restrict__ dtsum){
  __shared__ __align__(16) float bc[CLen][16];
  __shared__ __align__(16) float dr[CLen][8];
  __shared__ float us[192][CLen+1];
  int g = blockIdx.x;
  int b = g / (Kk*NCH); int k = (g / NCH) & 3; int ch = g % NCH;
  int l0 = ch * CLen;
  int t = threadIdx.x;             // t = d (0..191)
  const float* xb = xdbl + ((size_t)(b*Kk + k)*38)*Ll;
  for (int e = t; e < CLen*16; e += 192){ int n = e / CLen, ll = e % CLen;
    bc[ll][n] = xb[(6 + n)*Ll + l0 + ll]; }
  for (int e = t; e < CLen*6; e += 192){ int r = e / CLen, ll = e % CLen;
    dr[ll][r] = xb[r*Ll + l0 + ll]; }
  const float* ubase = ((k & 1) ? xiT : xi) + (size_t)b*Din*Ll;
  bool rev = (k >= 2);
  for (int e = t; e < 192*CLen; e += 192){
    int dd = e >> 5, ll = e & 31;
    int sp = rev ? (Ll-1 - l0 - ll) : (l0 + ll);
    us[dd][ll] = ubase[(size_t)dd*Ll + sp];
  }
  int d = t; int kd = k*Din + d;
  float dtw[6];
  #pragma unroll
  for (int r = 0; r < 6; r++) dtw[r] = dtw_g[kd*6 + r];
  float dtb = dtb_g[kd];
  float Ar[16];
  #pragma unroll
  for (int n = 0; n < 16; n++) Ar[n] = -__expf(Alog[kd*16 + n]);
  bool ok = true;
  #pragma unroll
  for (int n = 1; n < 16; n++)
    ok = ok && (fabsf(Ar[n] - (n+1)*Ar[0]) <= 1e-4f*fabsf(Ar[n]) + 1e-30f);
  float h[16];
  #pragma unroll
  for (int n = 0; n < 16; n++) h[n] = 0.f;
  float dts_acc = 0.f;
  __syncthreads();
  if (ok){
    for (int ll = 0; ll < CLen; ll++){
      float4 q0 = *(const float4*)&dr[ll][0];
      float4 q1 = *(const float4*)&dr[ll][4];
      float xv = dtb;
      xv = fmaf(dtw[0], q0.x, xv); xv = fmaf(dtw[1], q0.y, xv); xv = fmaf(dtw[2], q0.z, xv);
      xv = fmaf(dtw[3], q0.w, xv); xv = fmaf(dtw[4], q1.x, xv); xv = fmaf(dtw[5], q1.y, xv);
      float dt = softplusf_(xv);
      float u = us[d][ll];
      float dtu = dt * u;
      float e1 = __expf(dt * Ar[0]);
      float e2=e1*e1, e4=e2*e2, e8=e4*e4;
      float dA[16];
      dA[0]=e1; dA[1]=e2; dA[2]=e2*e1; dA[3]=e4; dA[4]=e4*e1; dA[5]=e4*e2; dA[6]=e4*e2*e1;
      dA[7]=e8; dA[8]=e8*e1; dA[9]=e8*e2; dA[10]=e8*e2*e1; dA[11]=e8*e4; dA[12]=e8*e4*e1;
      dA[13]=e8*e4*e2; dA[14]=e8*e4*e2*e1; dA[15]=e8*e8;
      float4 B0 = *(const float4*)&bc[ll][0];
      float4 B1 = *(const float4*)&bc[ll][4];
      float4 B2 = *(const float4*)&bc[ll][8];
      float4 B3 = *(const float4*)&bc[ll][12];
      float Bv[16] = {B0.x,B0.y,B0.z,B0.w,B1.x,B1.y,B1.z,B1.w,
                      B2.x,B2.y,B2.z,B2.w,B3.x,B3.y,B3.z,B3.w};
      #pragma unroll
      for (int n = 0; n < 16; n++) h[n] = fmaf(h[n], dA[n], dtu * Bv[n]);
      dts_acc += dt;
    }
  } else {
    for (int ll = 0; ll < CLen; ll++){
      float4 q0 = *(const float4*)&dr[ll][0];
      float4 q1 = *(const float4*)&dr[ll][4];
      float xv = dtb;
      xv = fmaf(dtw[0], q0.x, xv); xv = fmaf(dtw[1], q0.y, xv); xv = fmaf(dtw[2], q0.z, xv);
      xv = fmaf(dtw[3], q0.w, xv); xv = fmaf(dtw[4], q1.x, xv); xv = fmaf(dtw[5], q1.y, xv);
      float dt = softplusf_(xv);
      float u = us[d][ll];
      float dtu = dt * u;
      float4 B0 = *(const float4*)&bc[ll][0];
      float4 B1 = *(const float4*)&bc[ll][4];
      float4 B2 = *(const float4*)&bc[ll][8];
      float4 B3 = *(const float4*)&bc[ll][12];
      float Bv[16] = {B0.x,B0.y,B0.z,B0.w,B1.x,B1.y,B1.z,B1.w,
                      B2.x,B2.y,B2.z,B2.w,B3.x,B3.y,B3.z,B3.w};
      #pragma unroll
      for (int n = 0; n < 16; n++){
        float dA = __expf(dt * Ar[n]);
        h[n] = fmaf(h[n], dA, dtu * Bv[n]);
      }
      dts_acc += dt;
    }
  }
  float4* hp = (float4*)&hend[(((size_t)(b*Kk + k)*NCH + ch)*Din + d)*16];
  #pragma unroll
  for (int q = 0; q < 4; q++){
    float4 v; v.x = h[q*4]; v.y = h[q*4+1]; v.z = h[q*4+2]; v.w = h[q*4+3];
    hp[q] = v;
  }
  dtsum[((size_t)(b*Kk + k)*NCH + ch)*Din + d] = dts_acc;
}

// ---------------- K5: serial combine across chunks, IN-PLACE hend -> hin ----------------
__global__ __launch_bounds__(256) void k_combine(const float* __restrict__ Alog,
                                                 const float* __restrict__ dtsum,
                                                 float* __restrict__ hbuf){
  __shared__ float ds_s[NCH][17];
  int blk = blockIdx.x;
  int bk = blk / 12; int d0 = (blk % 12) * 16;   // Din*Ns/256 = 12
  int k = bk & 3;
  int t = threadIdx.x; int n = t & 15; int dd = t >> 4;  // dd 0..15
  int d = d0 + dd;
  for (int e = t; e < NCH*16; e += 256){ int c = e >> 4, di = e & 15;
    ds_s[c][di] = dtsum[(size_t)bk*NCH*Din + (size_t)c*Din + d0 + di]; }
  float A = -__expf(Alog[(k*Din + d)*16 + n]);
  __syncthreads();
  float h = 0.f;
  size_t base = ((size_t)bk*NCH*Din + d)*16 + n;       // + c*Din*16
  #pragma unroll 4
  for (int c = 0; c < NCH; c++){
    size_t idx = base + (size_t)c*(Din*16);
    float tmp = hbuf[idx];
    hbuf[idx] = h;                                     // prefix state (hin)
    h = fmaf(h, __expf(A * ds_s[c][dd]), tmp);
  }
}

// ---------------- K6: scan pass 2 — one direction per block; y via LDS -> coalesced store (round-14 form) ----------------
__global__ __launch_bounds__(192) void k_scany(const float* __restrict__ xi,
                                               const float* __restrict__ xiT,
                                               const float* __restrict__ xdbl,
                                               const float* __restrict__ dtw_g,
                                               const float* __restrict__ dtb_g,
                                               const float* __restrict__ Alog,
                                               const float* __restrict__ Ds_g,
                                               const float* __restrict__ hin,
                                               float* __restrict__ y0,
                                               float* __restrict__ y1,
                                               float* __restrict__ y2p,
                                               float* __restrict__ y3){
  // bc layout per ll: [0..15]=B, [16..31]=C, [32..37]=dt-raw (38,39 pad)
  __shared__ __align__(16) float bc[CLen][40];
  __shared__ float us[192][CLen+1];      // u on input; y on output (slot reused per step)
  int g = blockIdx.x;
  int b = g / (Kk*NCH); int k = (g / NCH) & 3; int ch = g % NCH;
  int l0 = ch * CLen; int t = threadIdx.x;
  const float* xb = xdbl + ((size_t)(b*Kk + k)*38)*Ll;
  for (int e = t; e < CLen*38; e += 192){
    int c = e / CLen, ll = e % CLen;
    int cp = (c < 6) ? (32 + c) : (c - 6);
    bc[ll][cp] = xb[c*Ll + l0 + ll];
  }
  const float* ubase = ((k & 1) ? xiT : xi) + (size_t)b*Din*Ll;
  bool rev = (k >= 2);
  for (int e = t; e < 192*CLen; e += 192){
    int dd = e >> 5, ll = e & 31;
    int sp = rev ? (Ll-1 - l0 - ll) : (l0 + ll);
    us[dd][ll] = ubase[(size_t)dd*Ll + sp];
  }
  int d = t; int kd = k*Din + d;
  float dtw[6];
  #pragma unroll
  for (int r = 0; r < 6; r++) dtw[r] = dtw_g[kd*6 + r];
  float dtb = dtb_g[kd];
  float Ar[16];
  #pragma unroll
  for (int n = 0; n < 16; n++) Ar[n] = -__expf(Alog[kd*16 + n]);
  bool ok = true;
  #pragma unroll
  for (int n = 1; n < 16; n++)
    ok = ok && (fabsf(Ar[n] - (n+1)*Ar[0]) <= 1e-4f*fabsf(Ar[n]) + 1e-30f);
  float Dk = Ds_g[kd];
  float h[16];
  {
    const float4* hp = (const float4*)&hin[(((size_t)(b*Kk + k)*NCH + ch)*Din + d)*16];
    #pragma unroll
    for (int q = 0; q < 4; q++){ float4 v = hp[q];
      h[q*4] = v.x; h[q*4+1] = v.y; h[q*4+2] = v.z; h[q*4+3] = v.w; }
  }
  __syncthreads();
  if (ok){
    for (int ll = 0; ll < CLen; ll++){
      float4 q0 = *(const float4*)&bc[ll][32];
      float4 q1 = *(const float4*)&bc[ll][36];
      float xv = dtb;
      xv = fmaf(dtw[0], q0.x, xv); xv = fmaf(dtw[1], q0.y, xv); xv = fmaf(dtw[2], q0.z, xv);
      xv = fmaf(dtw[3], q0.w, xv); xv = fmaf(dtw[4], q1.x, xv); xv = fmaf(dtw[5], q1.y, xv);
      float dt = softplusf_(xv);
      float u = us[d][ll];
      float dtu = dt * u;
      float e1 = __expf(dt * Ar[0]);
      float e2=e1*e1, e4=e2*e2, e8=e4*e4;
      float dA[16];
      dA[0]=e1; dA[1]=e2; dA[2]=e2*e1; dA[3]=e4; dA[4]=e4*e1; dA[5]=e4*e2; dA[6]=e4*e2*e1;
      dA[7]=e8; dA[8]=e8*e1; dA[9]=e8*e2; dA[10]=e8*e2*e1; dA[11]=e8*e4; dA[12]=e8*e4*e1;
      dA[13]=e8*e4*e2; dA[14]=e8*e4*e2*e1; dA[15]=e8*e8;
      float4 B0 = *(const float4*)&bc[ll][0];
      float4 B1 = *(const float4*)&bc[ll][4];
      float4 B2 = *(const float4*)&bc[ll][8];
      float4 B3 = *(const float4*)&bc[ll][12];
      float Bv[16] = {B0.x,B0.y,B0.z,B0.w,B1.x,B1.y,B1.z,B1.w,
                      B2.x,B2.y,B2.z,B2.w,B3.x,B3.y,B3.z,B3.w};
      #pragma unroll
      for (int n = 0; n < 16; n++) h[n] = fmaf(h[n], dA[n], dtu * Bv[n]);
      float4 C0 = *(const float4*)&bc[ll][16];
      float4 C1 = *(const float4*)&bc[ll][20];
      float4 C2 = *(const float4*)&bc[ll][24];
      float4 C3 = *(const float4*)&bc[ll][28];
      float Cv[16] = {C0.x,C0.y,C0.z,C0.w,C1.x,C1.y,C1.z,C1.w,
                      C2.x,C2.y,C2.z,C2.w,C3.x,C3.y,C3.z,C3.w};
      float y = 0.f;
      #pragma unroll
      for (int n = 0; n < 16; n++) y = fmaf(h[n], Cv[n], y);
      y = fmaf(Dk, u, y);
      us[d][ll] = y;                      // reuse LDS slot (u consumed this step)
    }
  } else {
    for (int ll = 0; ll < CLen; ll++){
      float4 q0 = *(const float4*)&bc[ll][32];
      float4 q1 = *(const float4*)&bc[ll][36];
      float xv = dtb;
      xv = fmaf(dtw[0], q0.x, xv); xv = fmaf(dtw[1], q0.y, xv); xv = fmaf(dtw[2], q0.z, xv);
      xv = fmaf(dtw[3], q0.w, xv); xv = fmaf(dtw[4], q1.x, xv); xv = fmaf(dtw[5], q1.y, xv);
      float dt = softplusf_(xv);
      float u = us[d][ll];
      float dtu = dt * u;
      float4 B0 = *(const float4*)&bc[ll][0];
      float4 B1 = *(const float4*)&bc[ll][4];
      float4 B2 = *(const float4*)&bc[ll][8];
      float4 B3 = *(const float4*)&bc[ll][12];
      float Bv[16] = {B0.x,B0.y,B0.z,B0.w,B1.x,B1.y,B1.z,B1.w,
                      B2.x,B2.y,B2.z,B2.w,B3.x,B3.y,B3.z,B3.w};
      #pragma unroll
      for (int n = 0; n < 16; n++){
        float dA = __expf(dt * Ar[n]);
        h[n] = fmaf(h[n], dA, dtu * Bv[n]);
      }
      float4 C0 = *(const float4*)&bc[ll][16];
      float4 C1 = *(const float4*)&bc[ll][20];
      float4 C2 = *(const float4*)&bc[ll][24];
      float4 C3 = *(const float4*)&bc[ll][28];
      float Cv[16] = {C0.x,C0.y,C0.z,C0.w,C1.x,C1.y,C1.z,C1.w,
                      C2.x,C2.y,C2.z,C2.w,C3.x,C3.y,C3.z,C3.w};
      float y = 0.f;
      #pragma unroll
      for (int n = 0; n < 16; n++) y = fmaf(h[n], Cv[n], y);
      y = fmaf(Dk, u, y);
      us[d][ll] = y;
    }
  }
  __syncthreads();
  // coalesced write-out: mirrors the staging loop (32-lane groups, 128B contiguous)
  float* yplane = (k == 0 ? y0 : k == 1 ? y1 : k == 2 ? y2p : y3) + (size_t)b*Din*Ll;
  for (int e = t; e < 192*CLen; e += 192){
    int dd = e >> 5, ll = e & 31;
    int sp = rev ? (Ll-1 - l0 - ll) : (l0 + ll);
    yplane[(size_t)dd*Ll + sp] = us[dd][ll];
  }
}

// ---------------- K7: merge y0 += y2p + T(y1 + y3), in place ----------------
__global__ __launch_bounds__(256) void k_merge(float* __restrict__ y0,
                                               const float* __restrict__ y1,
                                               const float* __restrict__ y2p,
                                               const float* __restrict__ y3){
  __shared__ float pl[64][65];
  int g = blockIdx.x;
  int t = threadIdx.x;
  const float* s1 = y1 + (size_t)g*Ll;
  const float* s3 = y3 + (size_t)g*Ll;
  const float* s2 = y2p + (size_t)g*Ll;
  float* dst = y0 + (size_t)g*Ll;
  #pragma unroll
  for (int i = 0; i < 16; i++){ int p = t + i*256; pl[p>>6][p&63] = s1[p] + s3[p]; }
  __syncthreads();
  #pragma unroll
  for (int i = 0; i < 16; i++){ int p = t + i*256; dst[p] += s2[p] + pl[p&63][p>>6]; }
}

// ---------------- K8: channel LayerNorm + gate (y * silu_z) ----------------
__global__ __launch_bounds__(256) void k_ln(const float* __restrict__ ycf,
                                            const float* __restrict__ zbuf,
                                            const float* __restrict__ gam,
                                            const float* __restrict__ bet,
                                            float* __restrict__ gbuf){
  __shared__ float sred[2][4][64];
  __shared__ float smu[64], srs[64];
  int g = blockIdx.x; int b = g >> 6; int l0 = (g & 63) * 64;
  int t = threadIdx.x; int lw = t & 63; int dg = t >> 6;
  size_t pbase = ((size_t)b*Din + dg*48)*Ll + l0 + lw;
  float sum = 0.f, ss = 0.f;
  for (int dd = 0; dd < 48; dd++){
    float v = ycf[pbase + (size_t)dd*Ll]; sum += v; ss = fmaf(v, v, ss);
  }
  sred[0][dg][lw] = sum; sred[1][dg][lw] = ss;
  __syncthreads();
  if (t < 64){
    float s = sred[0][0][t] + sred[0][1][t] + sred[0][2][t] + sred[0][3][t];
    float q = sred[1][0][t] + sred[1][1][t] + sred[1][2][t] + sred[1][3][t];
    float mu = s * (1.f/192.f);
    float var = q * (1.f/192.f) - mu*mu;
    smu[t] = mu; srs[t] = rsqrtf(var + EPSLN);
  }
  __syncthreads();
  float mu = smu[lw], rs = srs[lw];
  for (int dd = 0; dd < 48; dd++){
    int d = dg*48 + dd;
    float v = ycf[pbase + (size_t)dd*Ll];
    float vn = (v - mu)*rs*gam[d] + bet[d];
    float zz = zbuf[((size_t)b*Din + d)*Ll + l0 + lw];
    gbuf[((size_t)b*Din + d)*Ll + l0 + lw] = vn * zz;
  }
}

// ---------------- K9: 3 dilated depthwise convs + BN + ReLU -> cat ----------------
__global__ __launch_bounds__(256) void k_branch(const float* __restrict__ gbuf,
                                                const float* __restrict__ brw,
                                                const float* __restrict__ brg,
                                                const float* __restrict__ brb,
                                                float* __restrict__ cat){
  __shared__ float pl[64][65];
  int g = blockIdx.x; int b = g / Din, d = g % Din;
  int t = threadIdx.x;
  const float* src = gbuf + (size_t)g*Ll;
  #pragma unroll
  for (int i = 0; i < 16; i++){ int p = t + i*256; pl[p>>6][p&63] = src[p]; }
  float w[3][9]; float sc[3], bi[3];
  const float inv = rsqrtf(1.f + EPSBN);
  #pragma unroll
  for (int ib = 0; ib < 3; ib++){
    #pragma unroll
    for (int j = 0; j < 9; j++) w[ib][j] = brw[(ib*Din + d)*9 + j];
    sc[ib] = brg[ib*Din + d] * inv; bi[ib] = brb[ib*Din + d];
  }
  __syncthreads();
  const int dils[3] = {1, 2, 4};
  #pragma unroll
  for (int i = 0; i < 16; i++){
    int p = t + i*256; int h = p >> 6, wv = p & 63;
    #pragma unroll
    for (int ib = 0; ib < 3; ib++){
      int dil = dils[ib];
      float s = 0.f;
      #pragma unroll
      for (int r = 0; r < 3; r++){
        int hy = h + (r-1)*dil; if (hy < 0 || hy > 63) continue;
        #pragma unroll
        for (int c = 0; c < 3; c++){
          int wx = wv + (c-1)*dil; if (wx < 0 || wx > 63) continue;
          s = fmaf(pl[hy][wx], w[ib][r*3+c], s);
        }
      }
      s = s*sc[ib] + bi[ib];
      s = s > 0.f ? s : 0.f;
      cat[((size_t)b*576 + ib*Din + d)*Ll + p] = s;
    }
  }
}

// ---------------- K10: fuse 1x1 GEMM, M=64 N=96 K=32, 512 threads; cat read once ----------------
__global__ __launch_bounds__(512) void k_fuse(const float* __restrict__ cat,
                                              const float* __restrict__ fw,
                                              const float* __restrict__ fg,
                                              const float* __restrict__ fb,
                                              float* __restrict__ out){
  __shared__ float As[32][65];   // [k][m]  odd stride -> conflict-free
  __shared__ float Bs[32][97];   // [k][n]  odd stride -> conflict-free
  int t = threadIdx.x;
  int tx = t & 31, ty = t >> 5;              // tx -> n (0..31), ty -> m (0..15)
  int m0 = blockIdx.x * 64; int b = m0 >> 12; int l0 = m0 & 4095;
  float acc[4][3] = {};
  for (int k0 = 0; k0 < 576; k0 += 32){
    #pragma unroll
    for (int i = 0; i < 4; i++){ int e = t + i*512; int mm = e & 63, kk = e >> 6;
      As[kk][mm] = cat[((size_t)b*576 + k0 + kk)*Ll + l0 + mm]; }
    #pragma unroll
    for (int i = 0; i < 6; i++){ int e = t + i*512; int kk = e & 31, oo = e >> 5;
      Bs[kk][oo] = fw[(size_t)oo*576 + k0 + kk]; }
    __syncthreads();
    #pragma unroll
    for (int kk = 0; kk < 32; kk++){
      float a[4], bb[3];
      #pragma unroll
      for (int i = 0; i < 4; i++) a[i] = As[kk][ty + 16*i];
      #pragma unroll
      for (int j = 0; j < 3; j++) bb[j] = Bs[kk][tx + 32*j];
      #pragma unroll
      for (int i = 0; i < 4; i++)
        #pragma unroll
        for (int j = 0; j < 3; j++) acc[i][j] = fmaf(a[i], bb[j], acc[i][j]);
    }
    __syncthreads();
  }
  const float inv = rsqrtf(1.f + EPSBN);
  #pragma unroll
  for (int j = 0; j < 3; j++){
    int o = tx + 32*j;
    float sc = fg[o]*inv, bi = fb[o];
    #pragma unroll
    for (int i = 0; i < 4; i++){
      int m = m0 + ty + 16*i;
      float v = acc[i][j]*sc + bi;
      v = v > 0.f ? v : 0.f;
      out[(size_t)m*96 + o] = v;
    }
  }
}

// ---------------- diagnostic sentinel: ws too small even for G=1 ----------------
__global__ void k_sentinel(float* out, int n){
  int i = blockIdx.x*256 + threadIdx.x;
  if (i < n) out[i] = 1.5f;
}

// ---------------- launch ----------------
extern "C" void kernel_launch(void* const* d_in, const int* in_sizes, int n_in,
                              void* d_out, int out_size, void* d_ws, size_t ws_size,
                              hipStream_t stream){
  const float* x    = (const float*)d_in[0];
  const float* ipw  = (const float*)d_in[1];
  const float* cw   = (const float*)d_in[2];
  const float* cb   = (const float*)d_in[3];
  const float* xpw  = (const float*)d_in[4];
  const float* dtw  = (const float*)d_in[5];
  const float* dtb  = (const float*)d_in[6];
  const float* Alog = (const float*)d_in[7];
  const float* Ds   = (const float*)d_in[8];
  const float* ong  = (const float*)d_in[9];
  const float* onb  = (const float*)d_in[10];
  const float* brw  = (const float*)d_in[11];
  const float* brg  = (const float*)d_in[12];
  const float* brb  = (const float*)d_in[13];
  const float* fw   = (const float*)d_in[14];
  const float* fg   = (const float*)d_in[15];
  const float* fb   = (const float*)d_in[16];
  float* out = (float*)d_out;          // reference output dtype = float32

  // per-batch float counts
  const size_t P1     = (size_t)Din*Ll;        //   786,432 (one plane)
  const size_t S_xdbl = (size_t)Kk*38*Ll;      //   622,592
  const size_t S_h    = (size_t)Kk*NCH*Din*Ns; // 1,572,864
  const size_t S_dts  = (size_t)Kk*NCH*Din;    //    98,304
  const size_t perb   = 7*P1 + S_xdbl + S_h + S_dts;  // 7,798,784 floats = 31.2 MB

  int G = 4;
  if (ws_size < 4*perb*sizeof(float)) G = 2;
  if (ws_size < 2*perb*sizeof(float)) G = 1;
  if (ws_size < 1*perb*sizeof(float)){
    k_sentinel<<<(out_size + 255)/256, 256, 0, stream>>>(out, out_size);
    return;
  }

  float* wsf = (float*)d_ws;
  for (int b0 = 0; b0 < Bn; b0 += G){
    int nb = (Bn - b0 < G) ? (Bn - b0) : G;
    size_t nbP = (size_t)nb*P1;
    float* zbuf  = wsf;                 // [nbP]  plane 0   (cat overlays planes 0-2)
    float* y0    = zbuf + nbP;          // [nbP]  plane 1
    float* y1    = y0   + nbP;          // [nbP]  plane 2
    float* y2p   = y1   + nbP;          // [nbP]  plane 3
    float* y3    = y2p  + nbP;          // [nbP]  plane 4
    float* xi    = y3   + nbP;          // [nbP]  plane 5 (xi_pre -> xi in place; later gbuf)
    float* xiT   = xi   + nbP;          // [nbP]  plane 6
    float* xdbl  = xiT  + nbP;          // [nb*S_xdbl]
    float* hbuf  = xdbl + (size_t)nb*S_xdbl;  // [nb*S_h] (hend -> hin in place)
    float* dtsum = hbuf + (size_t)nb*S_h;     // [nb*S_dts]
    float* cat   = wsf;                 // [3*nbP] == nb*576*Ll exactly (planes 0-2)
    float* gbuf  = xi;

    const float* xg = x + (size_t)b0*Ll*96;
    float* outg = out + (size_t)b0*Ll*96;

    k_inproj <<<dim3(nb*64, 6), 256, 0, stream>>>(xg, ipw, xi, zbuf);
    k_dwconv <<<nb*Din, 256, 0, stream>>>(xi, cw, cb, xiT);
    k_xdbl   <<<nb*128, 256, 0, stream>>>(xi, xiT, xpw, xdbl);
    k_scan1  <<<nb*Kk*NCH, 192, 0, stream>>>(xi, xiT, xdbl, dtw, dtb, Alog, hbuf, dtsum);
    k_combine<<<nb*48, 256, 0, stream>>>(Alog, dtsum, hbuf);
    k_scany  <<<nb*Kk*NCH, 192, 0, stream>>>(xi, xiT, xdbl, dtw, dtb, Alog, Ds, hbuf,
                                             y0, y1, y2p, y3);
    k_merge  <<<nb*Din, 256, 0, stream>>>(y0, y1, y2p, y3);
    k_ln     <<<nb*64, 256, 0, stream>>>(y0, zbuf, ong, onb, gbuf);
    k_branch <<<nb*Din, 256, 0, stream>>>(gbuf, brw, brg, brb, cat);
    k_fuse   <<<nb*64, 512, 0, stream>>>(cat, fw, fg, fb, outg);
  }
}

// Round 17
// 264.815 us; speedup vs baseline: 1.1531x; 1.0132x over previous
//
#include <hip/hip_runtime.h>
#include <hip/hip_bf16.h>
#include <math.h>

// ---------------- constants (problem-fixed shapes) ----------------
constexpr int Bn  = 4;      // batch
constexpr int Din = 192;    // d_inner
constexpr int Ll  = 4096;   // L = H*W
constexpr int Kk  = 4;      // scan directions
constexpr int Ns  = 16;     // d_state
constexpr int NCH = 128;    // scan chunks
constexpr int CLen= 32;     // chunk length
constexpr float EPSBN = 1e-5f;
constexpr float EPSLN = 1e-5f;

#define DEV __device__ __forceinline__

DEV float siluf_(float x){ return x / (1.f + __expf(-x)); }
DEV float softplusf_(float x){ return x > 15.f ? x : __logf(1.f + __expf(x)); }

// ---------------- K1: in_proj GEMM (nb*4096 x 96 @ 96 x 384^T) + split + silu(z) ----------------
__global__ __launch_bounds__(256) void k_inproj(const float* __restrict__ x,
                                                const float* __restrict__ w,
                                                float* __restrict__ xi_pre,
                                                float* __restrict__ zbuf){
  __shared__ __align__(16) float As[32][72];
  __shared__ __align__(16) float Bs[32][72];
  int t = threadIdx.x, tx = t & 15, ty = t >> 4;
  int m0 = blockIdx.x * 64, o0 = blockIdx.y * 64;
  float acc[4][4] = {};
  for (int k0 = 0; k0 < 96; k0 += 32){
    #pragma unroll
    for (int i = 0; i < 8; i++){ int e = t + i*256; int kk = e & 31, mm = e >> 5;
      As[kk][mm] = x[(size_t)(m0+mm)*96 + k0+kk]; }
    #pragma unroll
    for (int i = 0; i < 8; i++){ int e = t + i*256; int kk = e & 31, nn = e >> 5;
      Bs[kk][nn] = w[(size_t)(o0+nn)*96 + k0+kk]; }
    __syncthreads();
    #pragma unroll
    for (int kk = 0; kk < 32; kk++){
      float a[4], bb[4];
      #pragma unroll
      for (int i = 0; i < 4; i++) a[i]  = As[kk][tx + 16*i];
      #pragma unroll
      for (int j = 0; j < 4; j++) bb[j] = Bs[kk][ty + 16*j];
      #pragma unroll
      for (int i = 0; i < 4; i++)
        #pragma unroll
        for (int j = 0; j < 4; j++) acc[i][j] = fmaf(a[i], bb[j], acc[i][j]);
    }
    __syncthreads();
  }
  #pragma unroll
  for (int i = 0; i < 4; i++){
    int m = m0 + tx + 16*i; int b = m >> 12, l = m & 4095;
    #pragma unroll
    for (int j = 0; j < 4; j++){
      int o = o0 + ty + 16*j; float v = acc[i][j];
      if (o < Din) xi_pre[((size_t)b*Din + o)*Ll + l] = v;
      else         zbuf[((size_t)b*Din + (o-Din))*Ll + l] = siluf_(v);
    }
  }
}

// ---------------- K2: depthwise 3x3 conv + bias + silu; IN-PLACE xi, also emits xiT ----------------
__global__ __launch_bounds__(256) void k_dwconv(float* __restrict__ xi,
                                                const float* __restrict__ cw,
                                                const float* __restrict__ cb,
                                                float* __restrict__ xiT){
  __shared__ float pl[64][65];
  __shared__ float po[64][65];
  int g = blockIdx.x; int d = g % Din;
  int t = threadIdx.x;
  float* plane = xi + (size_t)g*Ll;
  #pragma unroll
  for (int i = 0; i < 16; i++){ int p = t + i*256; pl[p>>6][p&63] = plane[p]; }
  float w9[9];
  #pragma unroll
  for (int j = 0; j < 9; j++) w9[j] = cw[d*9 + j];
  float bias = cb[d];
  __syncthreads();
  float out[16];
  #pragma unroll
  for (int i = 0; i < 16; i++){
    int p = t + i*256; int h = p >> 6, wv = p & 63;
    float s = bias;
    #pragma unroll
    for (int r = 0; r < 3; r++){
      int hy = h + r - 1; if (hy < 0 || hy > 63) continue;
      #pragma unroll
      for (int c = 0; c < 3; c++){
        int wx = wv + c - 1; if (wx < 0 || wx > 63) continue;
        s = fmaf(pl[hy][wx], w9[r*3+c], s);
      }
    }
    out[i] = siluf_(s);
  }
  __syncthreads();
  #pragma unroll
  for (int i = 0; i < 16; i++){ int p = t + i*256; po[p>>6][p&63] = out[i]; plane[p] = out[i]; }
  __syncthreads();
  float* dxt = xiT + (size_t)g*Ll;
  #pragma unroll
  for (int i = 0; i < 16; i++){ int p = t + i*256; dxt[p] = po[p&63][p>>6]; }
}

// ---------------- K3: x_dbl = einsum('bkdl,kcd->bkcl') — r12 shape + register prefetch ----------------
__global__ __launch_bounds__(256) void k_xdbl(const float* __restrict__ xi,
                                              const float* __restrict__ xiT,
                                              const float* __restrict__ xpw,
                                              float* __restrict__ xdbl){
  __shared__ float us[24][132];
  __shared__ __align__(16) float wl[24][40];
  int g = blockIdx.x; int b = g >> 7; int k = (g >> 5) & 3; int lt = g & 31;
  int l0 = lt * 128; int t = threadIdx.x;
  int lw = t & 127; int cg = t >> 7;          // c-group 0/1 (c = cg*20 .. +19)
  const float* src = (k & 1) ? xiT : xi;
  bool rev = (k >= 2);
  if (t < 48){ wl[t >> 1][38 + (t & 1)] = 0.f; }   // pad cols, written once
  float acc[20];
  #pragma unroll
  for (int j = 0; j < 20; j++) acc[j] = 0.f;
  float upf[12]; float wpf[4];
  // prefetch chunk 0
  #pragma unroll
  for (int i = 0; i < 12; i++){ int e = t + i*256; int dd = e >> 7, ll = e & 127;
    int sp = rev ? (4095 - (l0 + ll)) : (l0 + ll);
    upf[i] = src[((size_t)b*Din + dd)*Ll + sp]; }
  #pragma unroll
  for (int i = 0; i < 4; i++){ int e = t + i*256;
    if (e < 912){ int dd = e % 24, c = e / 24; wpf[i] = xpw[(k*38 + c)*Din + dd]; } }
  for (int dc = 0; dc < 8; dc++){
    #pragma unroll
    for (int i = 0; i < 12; i++){ int e = t + i*256; us[e >> 7][e & 127] = upf[i]; }
    #pragma unroll
    for (int i = 0; i < 4; i++){ int e = t + i*256;
      if (e < 912){ wl[e % 24][e / 24] = wpf[i]; } }
    __syncthreads();
    if (dc < 7){
      int d0n = (dc + 1) * 24;
      #pragma unroll
      for (int i = 0; i < 12; i++){ int e = t + i*256; int dd = e >> 7, ll = e & 127;
        int sp = rev ? (4095 - (l0 + ll)) : (l0 + ll);
        upf[i] = src[((size_t)b*Din + d0n + dd)*Ll + sp]; }
      #pragma unroll
      for (int i = 0; i < 4; i++){ int e = t + i*256;
        if (e < 912){ int dd = e % 24, c = e / 24; wpf[i] = xpw[(k*38 + c)*Din + d0n + dd]; } }
    }
    #pragma unroll
    for (int dd = 0; dd < 24; dd++){
      float u = us[dd][lw];
      const float4* wp = (const float4*)&wl[dd][cg*20];
      #pragma unroll
      for (int q = 0; q < 5; q++){
        float4 w4 = wp[q];
        acc[q*4+0] = fmaf(u, w4.x, acc[q*4+0]);
        acc[q*4+1] = fmaf(u, w4.y, acc[q*4+1]);
        acc[q*4+2] = fmaf(u, w4.z, acc[q*4+2]);
        acc[q*4+3] = fmaf(u, w4.w, acc[q*4+3]);
      }
    }
    __syncthreads();
  }
  float* dst = xdbl + ((size_t)(b*Kk + k)*38)*Ll + l0 + lw;
  #pragma unroll
  for (int j = 0; j < 20; j++){
    int c = cg*20 + j;
    if (c < 38) dst[(size_t)c*Ll] = acc[j];
  }
}

// ---------------- K4: scan pass 1 — per-chunk local end state + sum(dt)  (round-14 form) ----------------
__global__ __launch_bounds__(192) void k_scan1(const float* __restrict__ xi,
                                               const float* __restrict__ xiT,
                                               const float* __restrict__ xdbl,
                                               const float* __restrict__ dtw_g,
                                               const float* __restrict__ dtb_g,
                                               const float* __restrict__ Alog,
                                               float* __restrict__ hend,
                                               float* __restrict__ dtsum){
  __shared__ __align__(16) float bc[CLen][16];
  __shared__ __align__(16) float dr[CLen][8];
  __shared__ float us[192][CLen+1];
  int g = blockIdx.x;
  int b = g / (Kk*NCH); int k = (g / NCH) & 3; int ch = g % NCH;
  int l0 = ch * CLen;
  int t = threadIdx.x;             // t = d (0..191)
  const float* xb = xdbl + ((size_t)(b*Kk + k)*38)*Ll;
  for (int e = t; e < CLen*16; e += 192){ int n = e / CLen, ll = e % CLen;
    bc[ll][n] = xb[(6 + n)*Ll + l0 + ll]; }
  for (int e = t; e < CLen*6; e += 192){ int r = e / CLen, ll = e % CLen;
    dr[ll][r] = xb[r*Ll + l0 + ll]; }
  const float* ubase = ((k & 1) ? xiT : xi) + (size_t)b*Din*Ll;
  bool rev = (k >= 2);
  for (int e = t; e < 192*CLen; e += 192){
    int dd = e >> 5, ll = e & 31;
    int sp = rev ? (Ll-1 - l0 - ll) : (l0 + ll);
    us[dd][ll] = ubase[(size_t)dd*Ll + sp];
  }
  int d = t; int kd = k*Din + d;
  float dtw[6];
  #pragma unroll
  for (int r = 0; r < 6; r++) dtw[r] = dtw_g[kd*6 + r];
  float dtb = dtb_g[kd];
  float Ar[16];
  #pragma unroll
  for (int n = 0; n < 16; n++) Ar[n] = -__expf(Alog[kd*16 + n]);
  bool ok = true;
  #pragma unroll
  for (int n = 1; n < 16; n++)
    ok = ok && (fabsf(Ar[n] - (n+1)*Ar[0]) <= 1e-4f*fabsf(Ar[n]) + 1e-30f);
  float h[16];
  #pragma unroll
  for (int n = 0; n < 16; n++) h[n] = 0.f;
  float dts_acc = 0.f;
  __syncthreads();
  if (ok){
    for (int ll = 0; ll < CLen; ll++){
      float4 q0 = *(const float4*)&dr[ll][0];
      float4 q1 = *(const float4*)&dr[ll][4];
      float xv = dtb;
      xv = fmaf(dtw[0], q0.x, xv); xv = fmaf(dtw[1], q0.y, xv); xv = fmaf(dtw[2], q0.z, xv);
      xv = fmaf(dtw[3], q0.w, xv); xv = fmaf(dtw[4], q1.x, xv); xv = fmaf(dtw[5], q1.y, xv);
      float dt = softplusf_(xv);
      float u = us[d][ll];
      float dtu = dt * u;
      float e1 = __expf(dt * Ar[0]);
      float e2=e1*e1, e4=e2*e2, e8=e4*e4;
      float dA[16];
      dA[0]=e1; dA[1]=e2; dA[2]=e2*e1; dA[3]=e4; dA[4]=e4*e1; dA[5]=e4*e2; dA[6]=e4*e2*e1;
      dA[7]=e8; dA[8]=e8*e1; dA[9]=e8*e2; dA[10]=e8*e2*e1; dA[11]=e8*e4; dA[12]=e8*e4*e1;
      dA[13]=e8*e4*e2; dA[14]=e8*e4*e2*e1; dA[15]=e8*e8;
      float4 B0 = *(const float4*)&bc[ll][0];
      float4 B1 = *(const float4*)&bc[ll][4];
      float4 B2 = *(const float4*)&bc[ll][8];
      float4 B3 = *(const float4*)&bc[ll][12];
      float Bv[16] = {B0.x,B0.y,B0.z,B0.w,B1.x,B1.y,B1.z,B1.w,
                      B2.x,B2.y,B2.z,B2.w,B3.x,B3.y,B3.z,B3.w};
      #pragma unroll
      for (int n = 0; n < 16; n++) h[n] = fmaf(h[n], dA[n], dtu * Bv[n]);
      dts_acc += dt;
    }
  } else {
    for (int ll = 0; ll < CLen; ll++){
      float4 q0 = *(const float4*)&dr[ll][0];
      float4 q1 = *(const float4*)&dr[ll][4];
      float xv = dtb;
      xv = fmaf(dtw[0], q0.x, xv); xv = fmaf(dtw[1], q0.y, xv); xv = fmaf(dtw[2], q0.z, xv);
      xv = fmaf(dtw[3], q0.w, xv); xv = fmaf(dtw[4], q1.x, xv); xv = fmaf(dtw[5], q1.y, xv);
      float dt = softplusf_(xv);
      float u = us[d][ll];
      float dtu = dt * u;
      float4 B0 = *(const float4*)&bc[ll][0];
      float4 B1 = *(const float4*)&bc[ll][4];
      float4 B2 = *(const float4*)&bc[ll][8];
      float4 B3 = *(const float4*)&bc[ll][12];
      float Bv[16] = {B0.x,B0.y,B0.z,B0.w,B1.x,B1.y,B1.z,B1.w,
                      B2.x,B2.y,B2.z,B2.w,B3.x,B3.y,B3.z,B3.w};
      #pragma unroll
      for (int n = 0; n < 16; n++){
        float dA = __expf(dt * Ar[n]);
        h[n] = fmaf(h[n], dA, dtu * Bv[n]);
      }
      dts_acc += dt;
    }
  }
  float4* hp = (float4*)&hend[(((size_t)(b*Kk + k)*NCH + ch)*Din + d)*16];
  #pragma unroll
  for (int q = 0; q < 4; q++){
    float4 v; v.x = h[q*4]; v.y = h[q*4+1]; v.z = h[q*4+2]; v.w = h[q*4+3];
    hp[q] = v;
  }
  dtsum[((size_t)(b*Kk + k)*NCH + ch)*Din + d] = dts_acc;
}

// ---------------- K5: serial combine across chunks, IN-PLACE hend -> hin ----------------
__global__ __launch_bounds__(256) void k_combine(const float* __restrict__ Alog,
                                                 const float* __restrict__ dtsum,
                                                 float* __restrict__ hbuf){
  __shared__ float ds_s[NCH][17];
  int blk = blockIdx.x;
  int bk = blk / 12; int d0 = (blk % 12) * 16;   // Din*Ns/256 = 12
  int k = bk & 3;
  int t = threadIdx.x; int n = t & 15; int dd = t >> 4;  // dd 0..15
  int d = d0 + dd;
  for (int e = t; e < NCH*16; e += 256){ int c = e >> 4, di = e & 15;
    ds_s[c][di] = dtsum[(size_t)bk*NCH*Din + (size_t)c*Din + d0 + di]; }
  float A = -__expf(Alog[(k*Din + d)*16 + n]);
  __syncthreads();
  float h = 0.f;
  size_t base = ((size_t)bk*NCH*Din + d)*16 + n;       // + c*Din*16
  #pragma unroll 4
  for (int c = 0; c < NCH; c++){
    size_t idx = base + (size_t)c*(Din*16);
    float tmp = hbuf[idx];
    hbuf[idx] = h;                                     // prefix state (hin)
    h = fmaf(h, __expf(A * ds_s[c][dd]), tmp);
  }
}

// ---------------- K6: scan pass 2 — one direction per block; y via LDS -> coalesced store (round-14 form) ----------------
__global__ __launch_bounds__(192) void k_scany(const float* __restrict__ xi,
                                               const float* __restrict__ xiT,
                                               const float* __restrict__ xdbl,
                                               const float* __restrict__ dtw_g,
                                               const float* __restrict__ dtb_g,
                                               const float* __restrict__ Alog,
                                               const float* __restrict__ Ds_g,
                                               const float* __restrict__ hin,
                                               float* __restrict__ y0,
                                               float* __restrict__ y1,
                                               float* __restrict__ y2p,
                                               float* __restrict__ y3){
  // bc layout per ll: [0..15]=B, [16..31]=C, [32..37]=dt-raw (38,39 pad)
  __shared__ __align__(16) float bc[CLen][40];
  __shared__ float us[192][CLen+1];      // u on input; y on output (slot reused per step)
  int g = blockIdx.x;
  int b = g / (Kk*NCH); int k = (g / NCH) & 3; int ch = g % NCH;
  int l0 = ch * CLen; int t = threadIdx.x;
  const float* xb = xdbl + ((size_t)(b*Kk + k)*38)*Ll;
  for (int e = t; e < CLen*38; e += 192){
    int c = e / CLen, ll = e % CLen;
    int cp = (c < 6) ? (32 + c) : (c - 6);
    bc[ll][cp] = xb[c*Ll + l0 + ll];
  }
  const float* ubase = ((k & 1) ? xiT : xi) + (size_t)b*Din*Ll;
  bool rev = (k >= 2);
  for (int e = t; e < 192*CLen; e += 192){
    int dd = e >> 5, ll = e & 31;
    int sp = rev ? (Ll-1 - l0 - ll) : (l0 + ll);
    us[dd][ll] = ubase[(size_t)dd*Ll + sp];
  }
  int d = t; int kd = k*Din + d;
  float dtw[6];
  #pragma unroll
  for (int r = 0; r < 6; r++) dtw[r] = dtw_g[kd*6 + r];
  float dtb = dtb_g[kd];
  float Ar[16];
  #pragma unroll
  for (int n = 0; n < 16; n++) Ar[n] = -__expf(Alog[kd*16 + n]);
  bool ok = true;
  #pragma unroll
  for (int n = 1; n < 16; n++)
    ok = ok && (fabsf(Ar[n] - (n+1)*Ar[0]) <= 1e-4f*fabsf(Ar[n]) + 1e-30f);
  float Dk = Ds_g[kd];
  float h[16];
  {
    const float4* hp = (const float4*)&hin[(((size_t)(b*Kk + k)*NCH + ch)*Din + d)*16];
    #pragma unroll
    for (int q = 0; q < 4; q++){ float4 v = hp[q];
      h[q*4] = v.x; h[q*4+1] = v.y; h[q*4+2] = v.z; h[q*4+3] = v.w; }
  }
  __syncthreads();
  if (ok){
    for (int ll = 0; ll < CLen; ll++){
      float4 q0 = *(const float4*)&bc[ll][32];
      float4 q1 = *(const float4*)&bc[ll][36];
      float xv = dtb;
      xv = fmaf(dtw[0], q0.x, xv); xv = fmaf(dtw[1], q0.y, xv); xv = fmaf(dtw[2], q0.z, xv);
      xv = fmaf(dtw[3], q0.w, xv); xv = fmaf(dtw[4], q1.x, xv); xv = fmaf(dtw[5], q1.y, xv);
      float dt = softplusf_(xv);
      float u = us[d][ll];
      float dtu = dt * u;
      float e1 = __expf(dt * Ar[0]);
      float e2=e1*e1, e4=e2*e2, e8=e4*e4;
      float dA[16];
      dA[0]=e1; dA[1]=e2; dA[2]=e2*e1; dA[3]=e4; dA[4]=e4*e1; dA[5]=e4*e2; dA[6]=e4*e2*e1;
      dA[7]=e8; dA[8]=e8*e1; dA[9]=e8*e2; dA[10]=e8*e2*e1; dA[11]=e8*e4; dA[12]=e8*e4*e1;
      dA[13]=e8*e4*e2; dA[14]=e8*e4*e2*e1; dA[15]=e8*e8;
      float4 B0 = *(const float4*)&bc[ll][0];
      float4 B1 = *(const float4*)&bc[ll][4];
      float4 B2 = *(const float4*)&bc[ll][8];
      float4 B3 = *(const float4*)&bc[ll][12];
      float Bv[16] = {B0.x,B0.y,B0.z,B0.w,B1.x,B1.y,B1.z,B1.w,
                      B2.x,B2.y,B2.z,B2.w,B3.x,B3.y,B3.z,B3.w};
      #pragma unroll
      for (int n = 0; n < 16; n++) h[n] = fmaf(h[n], dA[n], dtu * Bv[n]);
      float4 C0 = *(const float4*)&bc[ll][16];
      float4 C1 = *(const float4*)&bc[ll][20];
      float4 C2 = *(const float4*)&bc[ll][24];
      float4 C3 = *(const float4*)&bc[ll][28];
      float Cv[16] = {C0.x,C0.y,C0.z,C0.w,C1.x,C1.y,C1.z,C1.w,
                      C2.x,C2.y,C2.z,C2.w,C3.x,C3.y,C3.z,C3.w};
      float y = 0.f;
      #pragma unroll
      for (int n = 0; n < 16; n++) y = fmaf(h[n], Cv[n], y);
      y = fmaf(Dk, u, y);
      us[d][ll] = y;                      // reuse LDS slot (u consumed this step)
    }
  } else {
    for (int ll = 0; ll < CLen; ll++){
      float4 q0 = *(const float4*)&bc[ll][32];
      float4 q1 = *(const float4*)&bc[ll][36];
      float xv = dtb;
      xv = fmaf(dtw[0], q0.x, xv); xv = fmaf(dtw[1], q0.y, xv); xv = fmaf(dtw[2], q0.z, xv);
      xv = fmaf(dtw[3], q0.w, xv); xv = fmaf(dtw[4], q1.x, xv); xv = fmaf(dtw[5], q1.y, xv);
      float dt = softplusf_(xv);
      float u = us[d][ll];
      float dtu = dt * u;
      float4 B0 = *(const float4*)&bc[ll][0];
      float4 B1 = *(const float4*)&bc[ll][4];
      float4 B2 = *(const float4*)&bc[ll][8];
      float4 B3 = *(const float4*)&bc[ll][12];
      float Bv[16] = {B0.x,B0.y,B0.z,B0.w,B1.x,B1.y,B1.z,B1.w,
                      B2.x,B2.y,B2.z,B2.w,B3.x,B3.y,B3.z,B3.w};
      #pragma unroll
      for (int n = 0; n < 16; n++){
        float dA = __expf(dt * Ar[n]);
        h[n] = fmaf(h[n], dA, dtu * Bv[n]);
      }
      float4 C0 = *(const float4*)&bc[ll][16];
      float4 C1 = *(const float4*)&bc[ll][20];
      float4 C2 = *(const float4*)&bc[ll][24];
      float4 C3 = *(const float4*)&bc[ll][28];
      float Cv[16] = {C0.x,C0.y,C0.z,C0.w,C1.x,C1.y,C1.z,C1.w,
                      C2.x,C2.y,C2.z,C2.w,C3.x,C3.y,C3.z,C3.w};
      float y = 0.f;
      #pragma unroll
      for (int n = 0; n < 16; n++) y = fmaf(h[n], Cv[n], y);
      y = fmaf(Dk, u, y);
      us[d][ll] = y;
    }
  }
  __syncthreads();
  // coalesced write-out: mirrors the staging loop (32-lane groups, 128B contiguous)
  float* yplane = (k == 0 ? y0 : k == 1 ? y1 : k == 2 ? y2p : y3) + (size_t)b*Din*Ll;
  for (int e = t; e < 192*CLen; e += 192){
    int dd = e >> 5, ll = e & 31;
    int sp = rev ? (Ll-1 - l0 - ll) : (l0 + ll);
    yplane[(size_t)dd*Ll + sp] = us[dd][ll];
  }
}

// ---------------- K7: merge y0 += y2p + T(y1 + y3), in place ----------------
__global__ __launch_bounds__(256) void k_merge(float* __restrict__ y0,
                                               const float* __restrict__ y1,
                                               const float* __restrict__ y2p,
                                               const float* __restrict__ y3){
  __shared__ float pl[64][65];
  int g = blockIdx.x;
  int t = threadIdx.x;
  const float* s1 = y1 + (size_t)g*Ll;
  const float* s3 = y3 + (size_t)g*Ll;
  const float* s2 = y2p + (size_t)g*Ll;
  float* dst = y0 + (size_t)g*Ll;
  #pragma unroll
  for (int i = 0; i < 16; i++){ int p = t + i*256; pl[p>>6][p&63] = s1[p] + s3[p]; }
  __syncthreads();
  #pragma unroll
  for (int i = 0; i < 16; i++){ int p = t + i*256; dst[p] += s2[p] + pl[p&63][p>>6]; }
}

// ---------------- K8: channel LayerNorm + gate (y * silu_z) ----------------
__global__ __launch_bounds__(256) void k_ln(const float* __restrict__ ycf,
                                            const float* __restrict__ zbuf,
                                            const float* __restrict__ gam,
                                            const float* __restrict__ bet,
                                            float* __restrict__ gbuf){
  __shared__ float sred[2][4][64];
  __shared__ float smu[64], srs[64];
  int g = blockIdx.x; int b = g >> 6; int l0 = (g & 63) * 64;
  int t = threadIdx.x; int lw = t & 63; int dg = t >> 6;
  size_t pbase = ((size_t)b*Din + dg*48)*Ll + l0 + lw;
  float sum = 0.f, ss = 0.f;
  for (int dd = 0; dd < 48; dd++){
    float v = ycf[pbase + (size_t)dd*Ll]; sum += v; ss = fmaf(v, v, ss);
  }
  sred[0][dg][lw] = sum; sred[1][dg][lw] = ss;
  __syncthreads();
  if (t < 64){
    float s = sred[0][0][t] + sred[0][1][t] + sred[0][2][t] + sred[0][3][t];
    float q = sred[1][0][t] + sred[1][1][t] + sred[1][2][t] + sred[1][3][t];
    float mu = s * (1.f/192.f);
    float var = q * (1.f/192.f) - mu*mu;
    smu[t] = mu; srs[t] = rsqrtf(var + EPSLN);
  }
  __syncthreads();
  float mu = smu[lw], rs = srs[lw];
  for (int dd = 0; dd < 48; dd++){
    int d = dg*48 + dd;
    float v = ycf[pbase + (size_t)dd*Ll];
    float vn = (v - mu)*rs*gam[d] + bet[d];
    float zz = zbuf[((size_t)b*Din + d)*Ll + l0 + lw];
    gbuf[((size_t)b*Din + d)*Ll + l0 + lw] = vn * zz;
  }
}

// ---------------- K9: 3 dilated depthwise convs + BN + ReLU -> cat ----------------
__global__ __launch_bounds__(256) void k_branch(const float* __restrict__ gbuf,
                                                const float* __restrict__ brw,
                                                const float* __restrict__ brg,
                                                const float* __restrict__ brb,
                                                float* __restrict__ cat){
  __shared__ float pl[64][65];
  int g = blockIdx.x; int b = g / Din, d = g % Din;
  int t = threadIdx.x;
  const float* src = gbuf + (size_t)g*Ll;
  #pragma unroll
  for (int i = 0; i < 16; i++){ int p = t + i*256; pl[p>>6][p&63] = src[p]; }
  float w[3][9]; float sc[3], bi[3];
  const float inv = rsqrtf(1.f + EPSBN);
  #pragma unroll
  for (int ib = 0; ib < 3; ib++){
    #pragma unroll
    for (int j = 0; j < 9; j++) w[ib][j] = brw[(ib*Din + d)*9 + j];
    sc[ib] = brg[ib*Din + d] * inv; bi[ib] = brb[ib*Din + d];
  }
  __syncthreads();
  const int dils[3] = {1, 2, 4};
  #pragma unroll
  for (int i = 0; i < 16; i++){
    int p = t + i*256; int h = p >> 6, wv = p & 63;
    #pragma unroll
    for (int ib = 0; ib < 3; ib++){
      int dil = dils[ib];
      float s = 0.f;
      #pragma unroll
      for (int r = 0; r < 3; r++){
        int hy = h + (r-1)*dil; if (hy < 0 || hy > 63) continue;
        #pragma unroll
        for (int c = 0; c < 3; c++){
          int wx = wv + (c-1)*dil; if (wx < 0 || wx > 63) continue;
          s = fmaf(pl[hy][wx], w[ib][r*3+c], s);
        }
      }
      s = s*sc[ib] + bi[ib];
      s = s > 0.f ? s : 0.f;
      cat[((size_t)b*576 + ib*Din + d)*Ll + p] = s;
    }
  }
}

// ---------------- K10: fuse 1x1 GEMM, M=64 N=96 K=32, 512 threads; float2 A-reads ----------------
__global__ __launch_bounds__(512) void k_fuse(const float* __restrict__ cat,
                                              const float* __restrict__ fw,
                                              const float* __restrict__ fg,
                                              const float* __restrict__ fb,
                                              float* __restrict__ out){
  __shared__ __align__(16) float As[32][66];   // [k][m]  row stride 264B (8B-aligned), 66 mod 32 = 2
  __shared__ float Bs[32][97];                 // [k][n]  odd stride -> conflict-free
  int t = threadIdx.x;
  int tx = t & 31, ty = t >> 5;                // tx -> n (0..31), ty -> m-pair (0..15)
  int m0 = blockIdx.x * 64; int b = m0 >> 12; int l0 = m0 & 4095;
  float acc[4][3] = {};
  for (int k0 = 0; k0 < 576; k0 += 32){
    #pragma unroll
    for (int i = 0; i < 4; i++){ int e = t + i*512; int mm = e & 63, kk = e >> 6;
      As[kk][mm] = cat[((size_t)b*576 + k0 + kk)*Ll + l0 + mm]; }
    #pragma unroll
    for (int i = 0; i < 6; i++){ int e = t + i*512; int kk = e & 31, oo = e >> 5;
      Bs[kk][oo] = fw[(size_t)oo*576 + k0 + kk]; }
    __syncthreads();
    #pragma unroll
    for (int kk = 0; kk < 32; kk++){
      float2 a01 = *(const float2*)&As[kk][ty*2];        // m = ty*2, ty*2+1
      float2 a23 = *(const float2*)&As[kk][ty*2 + 32];   // m = ty*2+32, ty*2+33
      float a[4] = {a01.x, a01.y, a23.x, a23.y};
      float bb[3];
      #pragma unroll
      for (int j = 0; j < 3; j++) bb[j] = Bs[kk][tx + 32*j];
      #pragma unroll
      for (int i = 0; i < 4; i++)
        #pragma unroll
        for (int j = 0; j < 3; j++) acc[i][j] = fmaf(a[i], bb[j], acc[i][j]);
    }
    __syncthreads();
  }
  const float inv = rsqrtf(1.f + EPSBN);
  const int moff[4] = {0, 1, 32, 33};
  #pragma unroll
  for (int j = 0; j < 3; j++){
    int o = tx + 32*j;
    float sc = fg[o]*inv, bi = fb[o];
    #pragma unroll
    for (int i = 0; i < 4; i++){
      int m = m0 + ty*2 + moff[i];
      float v = acc[i][j]*sc + bi;
      v = v > 0.f ? v : 0.f;
      out[(size_t)m*96 + o] = v;
    }
  }
}

// ---------------- diagnostic sentinel: ws too small even for G=1 ----------------
__global__ void k_sentinel(float* out, int n){
  int i = blockIdx.x*256 + threadIdx.x;
  if (i < n) out[i] = 1.5f;
}

// ---------------- launch ----------------
extern "C" void kernel_launch(void* const* d_in, const int* in_sizes, int n_in,
                              void* d_out, int out_size, void* d_ws, size_t ws_size,
                              hipStream_t stream){
  const float* x    = (const float*)d_in[0];
  const float* ipw  = (const float*)d_in[1];
  const float* cw   = (const float*)d_in[2];
  const float* cb   = (const float*)d_in[3];
  const float* xpw  = (const float*)d_in[4];
  const float* dtw  = (const float*)d_in[5];
  const float* dtb  = (const float*)d_in[6];
  const float* Alog = (const float*)d_in[7];
  const float* Ds   = (const float*)d_in[8];
  const float* ong  = (const float*)d_in[9];
  const float* onb  = (const float*)d_in[10];
  const float* brw  = (const float*)d_in[11];
  const float* brg  = (const float*)d_in[12];
  const float* brb  = (const float*)d_in[13];
  const float* fw   = (const float*)d_in[14];
  const float* fg   = (const float*)d_in[15];
  const float* fb   = (const float*)d_in[16];
  float* out = (float*)d_out;          // reference output dtype = float32

  // per-batch float counts
  const size_t P1     = (size_t)Din*Ll;        //   786,432 (one plane)
  const size_t S_xdbl = (size_t)Kk*38*Ll;      //   622,592
  const size_t S_h    = (size_t)Kk*NCH*Din*Ns; // 1,572,864
  const size_t S_dts  = (size_t)Kk*NCH*Din;    //    98,304
  const size_t perb   = 7*P1 + S_xdbl + S_h + S_dts;  // 7,798,784 floats = 31.2 MB

  int G = 4;
  if (ws_size < 4*perb*sizeof(float)) G = 2;
  if (ws_size < 2*perb*sizeof(float)) G = 1;
  if (ws_size < 1*perb*sizeof(float)){
    k_sentinel<<<(out_size + 255)/256, 256, 0, stream>>>(out, out_size);
    return;
  }

  float* wsf = (float*)d_ws;
  for (int b0 = 0; b0 < Bn; b0 += G){
    int nb = (Bn - b0 < G) ? (Bn - b0) : G;
    size_t nbP = (size_t)nb*P1;
    float* zbuf  = wsf;                 // [nbP]  plane 0   (cat overlays planes 0-2)
    float* y0    = zbuf + nbP;          // [nbP]  plane 1
    float* y1    = y0   + nbP;          // [nbP]  plane 2
    float* y2p   = y1   + nbP;          // [nbP]  plane 3
    float* y3    = y2p  + nbP;          // [nbP]  plane 4
    float* xi    = y3   + nbP;          // [nbP]  plane 5 (xi_pre -> xi in place; later gbuf)
    float* xiT   = xi   + nbP;          // [nbP]  plane 6
    float* xdbl  = xiT  + nbP;          // [nb*S_xdbl]
    float* hbuf  = xdbl + (size_t)nb*S_xdbl;  // [nb*S_h] (hend -> hin in place)
    float* dtsum = hbuf + (size_t)nb*S_h;     // [nb*S_dts]
    float* cat   = wsf;                 // [3*nbP] == nb*576*Ll exactly (planes 0-2)
    float* gbuf  = xi;

    const float* xg = x + (size_t)b0*Ll*96;
    float* outg = out + (size_t)b0*Ll*96;

    k_inproj <<<dim3(nb*64, 6), 256, 0, stream>>>(xg, ipw, xi, zbuf);
    k_dwconv <<<nb*Din, 256, 0, stream>>>(xi, cw, cb, xiT);
    k_xdbl   <<<nb*128, 256, 0, stream>>>(xi, xiT, xpw, xdbl);
    k_scan1  <<<nb*Kk*NCH, 192, 0, stream>>>(xi, xiT, xdbl, dtw, dtb, Alog, hbuf, dtsum);
    k_combine<<<nb*48, 256, 0, stream>>>(Alog, dtsum, hbuf);
    k_scany  <<<nb*Kk*NCH, 192, 0, stream>>>(xi, xiT, xdbl, dtw, dtb, Alog, Ds, hbuf,
                                             y0, y1, y2p, y3);
    k_merge  <<<nb*Din, 256, 0, stream>>>(y0, y1, y2p, y3);
    k_ln     <<<nb*64, 256, 0, stream>>>(y0, zbuf, ong, onb, gbuf);
    k_branch <<<nb*Din, 256, 0, stream>>>(gbuf, brw, brg, brb, cat);
    k_fuse   <<<nb*64, 512, 0, stream>>>(cat, fw, fg, fb, outg);
  }
}

// Round 18
// 263.587 us; speedup vs baseline: 1.1585x; 1.0047x over previous
//
#include <hip/hip_runtime.h>
#include <hip/hip_bf16.h>
#include <math.h>

// ---------------- constants (problem-fixed shapes) ----------------
constexpr int Bn  = 4;      // batch
constexpr int Din = 192;    // d_inner
constexpr int Ll  = 4096;   // L = H*W
constexpr int Kk  = 4;      // scan directions
constexpr int Ns  = 16;     // d_state
constexpr int NCH = 128;    // scan chunks
constexpr int CLen= 32;     // chunk length
constexpr float EPSBN = 1e-5f;
constexpr float EPSLN = 1e-5f;

#define DEV __device__ __forceinline__

DEV float siluf_(float x){ return x / (1.f + __expf(-x)); }
DEV float softplusf_(float x){ return x > 15.f ? x : __logf(1.f + __expf(x)); }

// ---------------- K1: in_proj GEMM (nb*4096 x 96 @ 96 x 384^T) + split + silu(z) ----------------
__global__ __launch_bounds__(256) void k_inproj(const float* __restrict__ x,
                                                const float* __restrict__ w,
                                                float* __restrict__ xi_pre,
                                                float* __restrict__ zbuf){
  __shared__ __align__(16) float As[32][72];
  __shared__ __align__(16) float Bs[32][72];
  int t = threadIdx.x, tx = t & 15, ty = t >> 4;
  int m0 = blockIdx.x * 64, o0 = blockIdx.y * 64;
  float acc[4][4] = {};
  for (int k0 = 0; k0 < 96; k0 += 32){
    #pragma unroll
    for (int i = 0; i < 8; i++){ int e = t + i*256; int kk = e & 31, mm = e >> 5;
      As[kk][mm] = x[(size_t)(m0+mm)*96 + k0+kk]; }
    #pragma unroll
    for (int i = 0; i < 8; i++){ int e = t + i*256; int kk = e & 31, nn = e >> 5;
      Bs[kk][nn] = w[(size_t)(o0+nn)*96 + k0+kk]; }
    __syncthreads();
    #pragma unroll
    for (int kk = 0; kk < 32; kk++){
      float a[4], bb[4];
      #pragma unroll
      for (int i = 0; i < 4; i++) a[i]  = As[kk][tx + 16*i];
      #pragma unroll
      for (int j = 0; j < 4; j++) bb[j] = Bs[kk][ty + 16*j];
      #pragma unroll
      for (int i = 0; i < 4; i++)
        #pragma unroll
        for (int j = 0; j < 4; j++) acc[i][j] = fmaf(a[i], bb[j], acc[i][j]);
    }
    __syncthreads();
  }
  #pragma unroll
  for (int i = 0; i < 4; i++){
    int m = m0 + tx + 16*i; int b = m >> 12, l = m & 4095;
    #pragma unroll
    for (int j = 0; j < 4; j++){
      int o = o0 + ty + 16*j; float v = acc[i][j];
      if (o < Din) xi_pre[((size_t)b*Din + o)*Ll + l] = v;
      else         zbuf[((size_t)b*Din + (o-Din))*Ll + l] = siluf_(v);
    }
  }
}

// ---------------- K2: depthwise 3x3 conv + bias + silu; IN-PLACE xi, also emits xiT ----------------
__global__ __launch_bounds__(256) void k_dwconv(float* __restrict__ xi,
                                                const float* __restrict__ cw,
                                                const float* __restrict__ cb,
                                                float* __restrict__ xiT){
  __shared__ float pl[64][65];
  __shared__ float po[64][65];
  int g = blockIdx.x; int d = g % Din;
  int t = threadIdx.x;
  float* plane = xi + (size_t)g*Ll;
  #pragma unroll
  for (int i = 0; i < 16; i++){ int p = t + i*256; pl[p>>6][p&63] = plane[p]; }
  float w9[9];
  #pragma unroll
  for (int j = 0; j < 9; j++) w9[j] = cw[d*9 + j];
  float bias = cb[d];
  __syncthreads();
  float out[16];
  #pragma unroll
  for (int i = 0; i < 16; i++){
    int p = t + i*256; int h = p >> 6, wv = p & 63;
    float s = bias;
    #pragma unroll
    for (int r = 0; r < 3; r++){
      int hy = h + r - 1; if (hy < 0 || hy > 63) continue;
      #pragma unroll
      for (int c = 0; c < 3; c++){
        int wx = wv + c - 1; if (wx < 0 || wx > 63) continue;
        s = fmaf(pl[hy][wx], w9[r*3+c], s);
      }
    }
    out[i] = siluf_(s);
  }
  __syncthreads();
  #pragma unroll
  for (int i = 0; i < 16; i++){ int p = t + i*256; po[p>>6][p&63] = out[i]; plane[p] = out[i]; }
  __syncthreads();
  float* dxt = xiT + (size_t)g*Ll;
  #pragma unroll
  for (int i = 0; i < 16; i++){ int p = t + i*256; dxt[p] = po[p&63][p>>6]; }
}

// ---------------- K3: x_dbl = einsum('bkdl,kcd->bkcl') — r12 shape + register prefetch ----------------
__global__ __launch_bounds__(256) void k_xdbl(const float* __restrict__ xi,
                                              const float* __restrict__ xiT,
                                              const float* __restrict__ xpw,
                                              float* __restrict__ xdbl){
  __shared__ float us[24][132];
  __shared__ __align__(16) float wl[24][40];
  int g = blockIdx.x; int b = g >> 7; int k = (g >> 5) & 3; int lt = g & 31;
  int l0 = lt * 128; int t = threadIdx.x;
  int lw = t & 127; int cg = t >> 7;          // c-group 0/1 (c = cg*20 .. +19)
  const float* src = (k & 1) ? xiT : xi;
  bool rev = (k >= 2);
  if (t < 48){ wl[t >> 1][38 + (t & 1)] = 0.f; }   // pad cols, written once
  float acc[20];
  #pragma unroll
  for (int j = 0; j < 20; j++) acc[j] = 0.f;
  float upf[12]; float wpf[4];
  // prefetch chunk 0
  #pragma unroll
  for (int i = 0; i < 12; i++){ int e = t + i*256; int dd = e >> 7, ll = e & 127;
    int sp = rev ? (4095 - (l0 + ll)) : (l0 + ll);
    upf[i] = src[((size_t)b*Din + dd)*Ll + sp]; }
  #pragma unroll
  for (int i = 0; i < 4; i++){ int e = t + i*256;
    if (e < 912){ int dd = e % 24, c = e / 24; wpf[i] = xpw[(k*38 + c)*Din + dd]; } }
  for (int dc = 0; dc < 8; dc++){
    #pragma unroll
    for (int i = 0; i < 12; i++){ int e = t + i*256; us[e >> 7][e & 127] = upf[i]; }
    #pragma unroll
    for (int i = 0; i < 4; i++){ int e = t + i*256;
      if (e < 912){ wl[e % 24][e / 24] = wpf[i]; } }
    __syncthreads();
    if (dc < 7){
      int d0n = (dc + 1) * 24;
      #pragma unroll
      for (int i = 0; i < 12; i++){ int e = t + i*256; int dd = e >> 7, ll = e & 127;
        int sp = rev ? (4095 - (l0 + ll)) : (l0 + ll);
        upf[i] = src[((size_t)b*Din + d0n + dd)*Ll + sp]; }
      #pragma unroll
      for (int i = 0; i < 4; i++){ int e = t + i*256;
        if (e < 912){ int dd = e % 24, c = e / 24; wpf[i] = xpw[(k*38 + c)*Din + d0n + dd]; } }
    }
    #pragma unroll
    for (int dd = 0; dd < 24; dd++){
      float u = us[dd][lw];
      const float4* wp = (const float4*)&wl[dd][cg*20];
      #pragma unroll
      for (int q = 0; q < 5; q++){
        float4 w4 = wp[q];
        acc[q*4+0] = fmaf(u, w4.x, acc[q*4+0]);
        acc[q*4+1] = fmaf(u, w4.y, acc[q*4+1]);
        acc[q*4+2] = fmaf(u, w4.z, acc[q*4+2]);
        acc[q*4+3] = fmaf(u, w4.w, acc[q*4+3]);
      }
    }
    __syncthreads();
  }
  float* dst = xdbl + ((size_t)(b*Kk + k)*38)*Ll + l0 + lw;
  #pragma unroll
  for (int j = 0; j < 20; j++){
    int c = cg*20 + j;
    if (c < 38) dst[(size_t)c*Ll] = acc[j];
  }
}

// ---------------- K4: scan pass 1 — per-chunk local end state + sum(dt)  (round-14 form) ----------------
__global__ __launch_bounds__(192) void k_scan1(const float* __restrict__ xi,
                                               const float* __restrict__ xiT,
                                               const float* __restrict__ xdbl,
                                               const float* __restrict__ dtw_g,
                                               const float* __restrict__ dtb_g,
                                               const float* __restrict__ Alog,
                                               float* __restrict__ hend,
                                               float* __restrict__ dtsum){
  __shared__ __align__(16) float bc[CLen][16];
  __shared__ __align__(16) float dr[CLen][8];
  __shared__ float us[192][CLen+1];
  int g = blockIdx.x;
  int b = g / (Kk*NCH); int k = (g / NCH) & 3; int ch = g % NCH;
  int l0 = ch * CLen;
  int t = threadIdx.x;             // t = d (0..191)
  const float* xb = xdbl + ((size_t)(b*Kk + k)*38)*Ll;
  for (int e = t; e < CLen*16; e += 192){ int n = e / CLen, ll = e % CLen;
    bc[ll][n] = xb[(6 + n)*Ll + l0 + ll]; }
  for (int e = t; e < CLen*6; e += 192){ int r = e / CLen, ll = e % CLen;
    dr[ll][r] = xb[r*Ll + l0 + ll]; }
  const float* ubase = ((k & 1) ? xiT : xi) + (size_t)b*Din*Ll;
  bool rev = (k >= 2);
  for (int e = t; e < 192*CLen; e += 192){
    int dd = e >> 5, ll = e & 31;
    int sp = rev ? (Ll-1 - l0 - ll) : (l0 + ll);
    us[dd][ll] = ubase[(size_t)dd*Ll + sp];
  }
  int d = t; int kd = k*Din + d;
  float dtw[6];
  #pragma unroll
  for (int r = 0; r < 6; r++) dtw[r] = dtw_g[kd*6 + r];
  float dtb = dtb_g[kd];
  float Ar[16];
  #pragma unroll
  for (int n = 0; n < 16; n++) Ar[n] = -__expf(Alog[kd*16 + n]);
  bool ok = true;
  #pragma unroll
  for (int n = 1; n < 16; n++)
    ok = ok && (fabsf(Ar[n] - (n+1)*Ar[0]) <= 1e-4f*fabsf(Ar[n]) + 1e-30f);
  float h[16];
  #pragma unroll
  for (int n = 0; n < 16; n++) h[n] = 0.f;
  float dts_acc = 0.f;
  __syncthreads();
  if (ok){
    for (int ll = 0; ll < CLen; ll++){
      float4 q0 = *(const float4*)&dr[ll][0];
      float4 q1 = *(const float4*)&dr[ll][4];
      float xv = dtb;
      xv = fmaf(dtw[0], q0.x, xv); xv = fmaf(dtw[1], q0.y, xv); xv = fmaf(dtw[2], q0.z, xv);
      xv = fmaf(dtw[3], q0.w, xv); xv = fmaf(dtw[4], q1.x, xv); xv = fmaf(dtw[5], q1.y, xv);
      float dt = softplusf_(xv);
      float u = us[d][ll];
      float dtu = dt * u;
      float e1 = __expf(dt * Ar[0]);
      float e2=e1*e1, e4=e2*e2, e8=e4*e4;
      float dA[16];
      dA[0]=e1; dA[1]=e2; dA[2]=e2*e1; dA[3]=e4; dA[4]=e4*e1; dA[5]=e4*e2; dA[6]=e4*e2*e1;
      dA[7]=e8; dA[8]=e8*e1; dA[9]=e8*e2; dA[10]=e8*e2*e1; dA[11]=e8*e4; dA[12]=e8*e4*e1;
      dA[13]=e8*e4*e2; dA[14]=e8*e4*e2*e1; dA[15]=e8*e8;
      float4 B0 = *(const float4*)&bc[ll][0];
      float4 B1 = *(const float4*)&bc[ll][4];
      float4 B2 = *(const float4*)&bc[ll][8];
      float4 B3 = *(const float4*)&bc[ll][12];
      float Bv[16] = {B0.x,B0.y,B0.z,B0.w,B1.x,B1.y,B1.z,B1.w,
                      B2.x,B2.y,B2.z,B2.w,B3.x,B3.y,B3.z,B3.w};
      #pragma unroll
      for (int n = 0; n < 16; n++) h[n] = fmaf(h[n], dA[n], dtu * Bv[n]);
      dts_acc += dt;
    }
  } else {
    for (int ll = 0; ll < CLen; ll++){
      float4 q0 = *(const float4*)&dr[ll][0];
      float4 q1 = *(const float4*)&dr[ll][4];
      float xv = dtb;
      xv = fmaf(dtw[0], q0.x, xv); xv = fmaf(dtw[1], q0.y, xv); xv = fmaf(dtw[2], q0.z, xv);
      xv = fmaf(dtw[3], q0.w, xv); xv = fmaf(dtw[4], q1.x, xv); xv = fmaf(dtw[5], q1.y, xv);
      float dt = softplusf_(xv);
      float u = us[d][ll];
      float dtu = dt * u;
      float4 B0 = *(const float4*)&bc[ll][0];
      float4 B1 = *(const float4*)&bc[ll][4];
      float4 B2 = *(const float4*)&bc[ll][8];
      float4 B3 = *(const float4*)&bc[ll][12];
      float Bv[16] = {B0.x,B0.y,B0.z,B0.w,B1.x,B1.y,B1.z,B1.w,
                      B2.x,B2.y,B2.z,B2.w,B3.x,B3.y,B3.z,B3.w};
      #pragma unroll
      for (int n = 0; n < 16; n++){
        float dA = __expf(dt * Ar[n]);
        h[n] = fmaf(h[n], dA, dtu * Bv[n]);
      }
      dts_acc += dt;
    }
  }
  float4* hp = (float4*)&hend[(((size_t)(b*Kk + k)*NCH + ch)*Din + d)*16];
  #pragma unroll
  for (int q = 0; q < 4; q++){
    float4 v; v.x = h[q*4]; v.y = h[q*4+1]; v.z = h[q*4+2]; v.w = h[q*4+3];
    hp[q] = v;
  }
  dtsum[((size_t)(b*Kk + k)*NCH + ch)*Din + d] = dts_acc;
}

// ---------------- K5: serial combine across chunks, IN-PLACE hend -> hin ----------------
__global__ __launch_bounds__(256) void k_combine(const float* __restrict__ Alog,
                                                 const float* __restrict__ dtsum,
                                                 float* __restrict__ hbuf){
  __shared__ float ds_s[NCH][17];
  int blk = blockIdx.x;
  int bk = blk / 12; int d0 = (blk % 12) * 16;   // Din*Ns/256 = 12
  int k = bk & 3;
  int t = threadIdx.x; int n = t & 15; int dd = t >> 4;  // dd 0..15
  int d = d0 + dd;
  for (int e = t; e < NCH*16; e += 256){ int c = e >> 4, di = e & 15;
    ds_s[c][di] = dtsum[(size_t)bk*NCH*Din + (size_t)c*Din + d0 + di]; }
  float A = -__expf(Alog[(k*Din + d)*16 + n]);
  __syncthreads();
  float h = 0.f;
  size_t base = ((size_t)bk*NCH*Din + d)*16 + n;       // + c*Din*16
  #pragma unroll 4
  for (int c = 0; c < NCH; c++){
    size_t idx = base + (size_t)c*(Din*16);
    float tmp = hbuf[idx];
    hbuf[idx] = h;                                     // prefix state (hin)
    h = fmaf(h, __expf(A * ds_s[c][dd]), tmp);
  }
}

// ---------------- K6: scan pass 2 — one direction per block; y via LDS -> coalesced store (round-14 form) ----------------
__global__ __launch_bounds__(192) void k_scany(const float* __restrict__ xi,
                                               const float* __restrict__ xiT,
                                               const float* __restrict__ xdbl,
                                               const float* __restrict__ dtw_g,
                                               const float* __restrict__ dtb_g,
                                               const float* __restrict__ Alog,
                                               const float* __restrict__ Ds_g,
                                               const float* __restrict__ hin,
                                               float* __restrict__ y0,
                                               float* __restrict__ y1,
                                               float* __restrict__ y2p,
                                               float* __restrict__ y3){
  // bc layout per ll: [0..15]=B, [16..31]=C, [32..37]=dt-raw (38,39 pad)
  __shared__ __align__(16) float bc[CLen][40];
  __shared__ float us[192][CLen+1];      // u on input; y on output (slot reused per step)
  int g = blockIdx.x;
  int b = g / (Kk*NCH); int k = (g / NCH) & 3; int ch = g % NCH;
  int l0 = ch * CLen; int t = threadIdx.x;
  const float* xb = xdbl + ((size_t)(b*Kk + k)*38)*Ll;
  for (int e = t; e < CLen*38; e += 192){
    int c = e / CLen, ll = e % CLen;
    int cp = (c < 6) ? (32 + c) : (c - 6);
    bc[ll][cp] = xb[c*Ll + l0 + ll];
  }
  const float* ubase = ((k & 1) ? xiT : xi) + (size_t)b*Din*Ll;
  bool rev = (k >= 2);
  for (int e = t; e < 192*CLen; e += 192){
    int dd = e >> 5, ll = e & 31;
    int sp = rev ? (Ll-1 - l0 - ll) : (l0 + ll);
    us[dd][ll] = ubase[(size_t)dd*Ll + sp];
  }
  int d = t; int kd = k*Din + d;
  float dtw[6];
  #pragma unroll
  for (int r = 0; r < 6; r++) dtw[r] = dtw_g[kd*6 + r];
  float dtb = dtb_g[kd];
  float Ar[16];
  #pragma unroll
  for (int n = 0; n < 16; n++) Ar[n] = -__expf(Alog[kd*16 + n]);
  bool ok = true;
  #pragma unroll
  for (int n = 1; n < 16; n++)
    ok = ok && (fabsf(Ar[n] - (n+1)*Ar[0]) <= 1e-4f*fabsf(Ar[n]) + 1e-30f);
  float Dk = Ds_g[kd];
  float h[16];
  {
    const float4* hp = (const float4*)&hin[(((size_t)(b*Kk + k)*NCH + ch)*Din + d)*16];
    #pragma unroll
    for (int q = 0; q < 4; q++){ float4 v = hp[q];
      h[q*4] = v.x; h[q*4+1] = v.y; h[q*4+2] = v.z; h[q*4+3] = v.w; }
  }
  __syncthreads();
  if (ok){
    for (int ll = 0; ll < CLen; ll++){
      float4 q0 = *(const float4*)&bc[ll][32];
      float4 q1 = *(const float4*)&bc[ll][36];
      float xv = dtb;
      xv = fmaf(dtw[0], q0.x, xv); xv = fmaf(dtw[1], q0.y, xv); xv = fmaf(dtw[2], q0.z, xv);
      xv = fmaf(dtw[3], q0.w, xv); xv = fmaf(dtw[4], q1.x, xv); xv = fmaf(dtw[5], q1.y, xv);
      float dt = softplusf_(xv);
      float u = us[d][ll];
      float dtu = dt * u;
      float e1 = __expf(dt * Ar[0]);
      float e2=e1*e1, e4=e2*e2, e8=e4*e4;
      float dA[16];
      dA[0]=e1; dA[1]=e2; dA[2]=e2*e1; dA[3]=e4; dA[4]=e4*e1; dA[5]=e4*e2; dA[6]=e4*e2*e1;
      dA[7]=e8; dA[8]=e8*e1; dA[9]=e8*e2; dA[10]=e8*e2*e1; dA[11]=e8*e4; dA[12]=e8*e4*e1;
      dA[13]=e8*e4*e2; dA[14]=e8*e4*e2*e1; dA[15]=e8*e8;
      float4 B0 = *(const float4*)&bc[ll][0];
      float4 B1 = *(const float4*)&bc[ll][4];
      float4 B2 = *(const float4*)&bc[ll][8];
      float4 B3 = *(const float4*)&bc[ll][12];
      float Bv[16] = {B0.x,B0.y,B0.z,B0.w,B1.x,B1.y,B1.z,B1.w,
                      B2.x,B2.y,B2.z,B2.w,B3.x,B3.y,B3.z,B3.w};
      #pragma unroll
      for (int n = 0; n < 16; n++) h[n] = fmaf(h[n], dA[n], dtu * Bv[n]);
      float4 C0 = *(const float4*)&bc[ll][16];
      float4 C1 = *(const float4*)&bc[ll][20];
      float4 C2 = *(const float4*)&bc[ll][24];
      float4 C3 = *(const float4*)&bc[ll][28];
      float Cv[16] = {C0.x,C0.y,C0.z,C0.w,C1.x,C1.y,C1.z,C1.w,
                      C2.x,C2.y,C2.z,C2.w,C3.x,C3.y,C3.z,C3.w};
      float y = 0.f;
      #pragma unroll
      for (int n = 0; n < 16; n++) y = fmaf(h[n], Cv[n], y);
      y = fmaf(Dk, u, y);
      us[d][ll] = y;                      // reuse LDS slot (u consumed this step)
    }
  } else {
    for (int ll = 0; ll < CLen; ll++){
      float4 q0 = *(const float4*)&bc[ll][32];
      float4 q1 = *(const float4*)&bc[ll][36];
      float xv = dtb;
      xv = fmaf(dtw[0], q0.x, xv); xv = fmaf(dtw[1], q0.y, xv); xv = fmaf(dtw[2], q0.z, xv);
      xv = fmaf(dtw[3], q0.w, xv); xv = fmaf(dtw[4], q1.x, xv); xv = fmaf(dtw[5], q1.y, xv);
      float dt = softplusf_(xv);
      float u = us[d][ll];
      float dtu = dt * u;
      float4 B0 = *(const float4*)&bc[ll][0];
      float4 B1 = *(const float4*)&bc[ll][4];
      float4 B2 = *(const float4*)&bc[ll][8];
      float4 B3 = *(const float4*)&bc[ll][12];
      float Bv[16] = {B0.x,B0.y,B0.z,B0.w,B1.x,B1.y,B1.z,B1.w,
                      B2.x,B2.y,B2.z,B2.w,B3.x,B3.y,B3.z,B3.w};
      #pragma unroll
      for (int n = 0; n < 16; n++){
        float dA = __expf(dt * Ar[n]);
        h[n] = fmaf(h[n], dA, dtu * Bv[n]);
      }
      float4 C0 = *(const float4*)&bc[ll][16];
      float4 C1 = *(const float4*)&bc[ll][20];
      float4 C2 = *(const float4*)&bc[ll][24];
      float4 C3 = *(const float4*)&bc[ll][28];
      float Cv[16] = {C0.x,C0.y,C0.z,C0.w,C1.x,C1.y,C1.z,C1.w,
                      C2.x,C2.y,C2.z,C2.w,C3.x,C3.y,C3.z,C3.w};
      float y = 0.f;
      #pragma unroll
      for (int n = 0; n < 16; n++) y = fmaf(h[n], Cv[n], y);
      y = fmaf(Dk, u, y);
      us[d][ll] = y;
    }
  }
  __syncthreads();
  // coalesced write-out: mirrors the staging loop (32-lane groups, 128B contiguous)
  float* yplane = (k == 0 ? y0 : k == 1 ? y1 : k == 2 ? y2p : y3) + (size_t)b*Din*Ll;
  for (int e = t; e < 192*CLen; e += 192){
    int dd = e >> 5, ll = e & 31;
    int sp = rev ? (Ll-1 - l0 - ll) : (l0 + ll);
    yplane[(size_t)dd*Ll + sp] = us[dd][ll];
  }
}

// ---------------- K7: merge y0 += y2p + T(y1 + y3), in place ----------------
__global__ __launch_bounds__(256) void k_merge(float* __restrict__ y0,
                                               const float* __restrict__ y1,
                                               const float* __restrict__ y2p,
                                               const float* __restrict__ y3){
  __shared__ float pl[64][65];
  int g = blockIdx.x;
  int t = threadIdx.x;
  const float* s1 = y1 + (size_t)g*Ll;
  const float* s3 = y3 + (size_t)g*Ll;
  const float* s2 = y2p + (size_t)g*Ll;
  float* dst = y0 + (size_t)g*Ll;
  #pragma unroll
  for (int i = 0; i < 16; i++){ int p = t + i*256; pl[p>>6][p&63] = s1[p] + s3[p]; }
  __syncthreads();
  #pragma unroll
  for (int i = 0; i < 16; i++){ int p = t + i*256; dst[p] += s2[p] + pl[p&63][p>>6]; }
}

// ---------------- K8: channel LayerNorm + gate (y * silu_z) ----------------
__global__ __launch_bounds__(256) void k_ln(const float* __restrict__ ycf,
                                            const float* __restrict__ zbuf,
                                            const float* __restrict__ gam,
                                            const float* __restrict__ bet,
                                            float* __restrict__ gbuf){
  __shared__ float sred[2][4][64];
  __shared__ float smu[64], srs[64];
  int g = blockIdx.x; int b = g >> 6; int l0 = (g & 63) * 64;
  int t = threadIdx.x; int lw = t & 63; int dg = t >> 6;
  size_t pbase = ((size_t)b*Din + dg*48)*Ll + l0 + lw;
  float sum = 0.f, ss = 0.f;
  for (int dd = 0; dd < 48; dd++){
    float v = ycf[pbase + (size_t)dd*Ll]; sum += v; ss = fmaf(v, v, ss);
  }
  sred[0][dg][lw] = sum; sred[1][dg][lw] = ss;
  __syncthreads();
  if (t < 64){
    float s = sred[0][0][t] + sred[0][1][t] + sred[0][2][t] + sred[0][3][t];
    float q = sred[1][0][t] + sred[1][1][t] + sred[1][2][t] + sred[1][3][t];
    float mu = s * (1.f/192.f);
    float var = q * (1.f/192.f) - mu*mu;
    smu[t] = mu; srs[t] = rsqrtf(var + EPSLN);
  }
  __syncthreads();
  float mu = smu[lw], rs = srs[lw];
  for (int dd = 0; dd < 48; dd++){
    int d = dg*48 + dd;
    float v = ycf[pbase + (size_t)dd*Ll];
    float vn = (v - mu)*rs*gam[d] + bet[d];
    float zz = zbuf[((size_t)b*Din + d)*Ll + l0 + lw];
    gbuf[((size_t)b*Din + d)*Ll + l0 + lw] = vn * zz;
  }
}

// ---------------- K9: 3 dilated depthwise convs + BN + ReLU -> cat ----------------
__global__ __launch_bounds__(256) void k_branch(const float* __restrict__ gbuf,
                                                const float* __restrict__ brw,
                                                const float* __restrict__ brg,
                                                const float* __restrict__ brb,
                                                float* __restrict__ cat){
  __shared__ float pl[64][65];
  int g = blockIdx.x; int b = g / Din, d = g % Din;
  int t = threadIdx.x;
  const float* src = gbuf + (size_t)g*Ll;
  #pragma unroll
  for (int i = 0; i < 16; i++){ int p = t + i*256; pl[p>>6][p&63] = src[p]; }
  float w[3][9]; float sc[3], bi[3];
  const float inv = rsqrtf(1.f + EPSBN);
  #pragma unroll
  for (int ib = 0; ib < 3; ib++){
    #pragma unroll
    for (int j = 0; j < 9; j++) w[ib][j] = brw[(ib*Din + d)*9 + j];
    sc[ib] = brg[ib*Din + d] * inv; bi[ib] = brb[ib*Din + d];
  }
  __syncthreads();
  const int dils[3] = {1, 2, 4};
  #pragma unroll
  for (int i = 0; i < 16; i++){
    int p = t + i*256; int h = p >> 6, wv = p & 63;
    #pragma unroll
    for (int ib = 0; ib < 3; ib++){
      int dil = dils[ib];
      float s = 0.f;
      #pragma unroll
      for (int r = 0; r < 3; r++){
        int hy = h + (r-1)*dil; if (hy < 0 || hy > 63) continue;
        #pragma unroll
        for (int c = 0; c < 3; c++){
          int wx = wv + (c-1)*dil; if (wx < 0 || wx > 63) continue;
          s = fmaf(pl[hy][wx], w[ib][r*3+c], s);
        }
      }
      s = s*sc[ib] + bi[ib];
      s = s > 0.f ? s : 0.f;
      cat[((size_t)b*576 + ib*Din + d)*Ll + p] = s;
    }
  }
}

// ---------------- K10: fuse 1x1 GEMM, M=64 N=96 K=32, 512 threads; float2 A-reads + reg prefetch ----------------
__global__ __launch_bounds__(512) void k_fuse(const float* __restrict__ cat,
                                              const float* __restrict__ fw,
                                              const float* __restrict__ fg,
                                              const float* __restrict__ fb,
                                              float* __restrict__ out){
  __shared__ __align__(16) float As[32][66];   // [k][m]  row stride 264B (8B-aligned), 66 mod 32 = 2
  __shared__ float Bs[32][97];                 // [k][n]  odd stride -> conflict-free
  int t = threadIdx.x;
  int tx = t & 31, ty = t >> 5;                // tx -> n (0..31), ty -> m-pair (0..15)
  int m0 = blockIdx.x * 64; int b = m0 >> 12; int l0 = m0 & 4095;
  float acc[4][3] = {};
  float apf[4], bpf[6];
  // prefetch K-tile 0
  #pragma unroll
  for (int i = 0; i < 4; i++){ int e = t + i*512; int mm = e & 63, kk = e >> 6;
    apf[i] = cat[((size_t)b*576 + kk)*Ll + l0 + mm]; }
  #pragma unroll
  for (int i = 0; i < 6; i++){ int e = t + i*512; int kk = e & 31, oo = e >> 5;
    bpf[i] = fw[(size_t)oo*576 + kk]; }
  for (int k0 = 0; k0 < 576; k0 += 32){
    // write prefetched tile into LDS
    #pragma unroll
    for (int i = 0; i < 4; i++){ int e = t + i*512; As[e >> 6][e & 63] = apf[i]; }
    #pragma unroll
    for (int i = 0; i < 6; i++){ int e = t + i*512; Bs[e & 31][e >> 5] = bpf[i]; }
    __syncthreads();
    if (k0 < 544){
      int k0n = k0 + 32;
      #pragma unroll
      for (int i = 0; i < 4; i++){ int e = t + i*512; int mm = e & 63, kk = e >> 6;
        apf[i] = cat[((size_t)b*576 + k0n + kk)*Ll + l0 + mm]; }
      #pragma unroll
      for (int i = 0; i < 6; i++){ int e = t + i*512; int kk = e & 31, oo = e >> 5;
        bpf[i] = fw[(size_t)oo*576 + k0n + kk]; }
    }
    #pragma unroll
    for (int kk = 0; kk < 32; kk++){
      float2 a01 = *(const float2*)&As[kk][ty*2];        // m = ty*2, ty*2+1
      float2 a23 = *(const float2*)&As[kk][ty*2 + 32];   // m = ty*2+32, ty*2+33
      float a[4] = {a01.x, a01.y, a23.x, a23.y};
      float bb[3];
      #pragma unroll
      for (int j = 0; j < 3; j++) bb[j] = Bs[kk][tx + 32*j];
      #pragma unroll
      for (int i = 0; i < 4; i++)
        #pragma unroll
        for (int j = 0; j < 3; j++) acc[i][j] = fmaf(a[i], bb[j], acc[i][j]);
    }
    __syncthreads();
  }
  const float inv = rsqrtf(1.f + EPSBN);
  const int moff[4] = {0, 1, 32, 33};
  #pragma unroll
  for (int j = 0; j < 3; j++){
    int o = tx + 32*j;
    float sc = fg[o]*inv, bi = fb[o];
    #pragma unroll
    for (int i = 0; i < 4; i++){
      int m = m0 + ty*2 + moff[i];
      float v = acc[i][j]*sc + bi;
      v = v > 0.f ? v : 0.f;
      out[(size_t)m*96 + o] = v;
    }
  }
}

// ---------------- diagnostic sentinel: ws too small even for G=1 ----------------
__global__ void k_sentinel(float* out, int n){
  int i = blockIdx.x*256 + threadIdx.x;
  if (i < n) out[i] = 1.5f;
}

// ---------------- launch ----------------
extern "C" void kernel_launch(void* const* d_in, const int* in_sizes, int n_in,
                              void* d_out, int out_size, void* d_ws, size_t ws_size,
                              hipStream_t stream){
  const float* x    = (const float*)d_in[0];
  const float* ipw  = (const float*)d_in[1];
  const float* cw   = (const float*)d_in[2];
  const float* cb   = (const float*)d_in[3];
  const float* xpw  = (const float*)d_in[4];
  const float* dtw  = (const float*)d_in[5];
  const float* dtb  = (const float*)d_in[6];
  const float* Alog = (const float*)d_in[7];
  const float* Ds   = (const float*)d_in[8];
  const float* ong  = (const float*)d_in[9];
  const float* onb  = (const float*)d_in[10];
  const float* brw  = (const float*)d_in[11];
  const float* brg  = (const float*)d_in[12];
  const float* brb  = (const float*)d_in[13];
  const float* fw   = (const float*)d_in[14];
  const float* fg   = (const float*)d_in[15];
  const float* fb   = (const float*)d_in[16];
  float* out = (float*)d_out;          // reference output dtype = float32

  // per-batch float counts
  const size_t P1     = (size_t)Din*Ll;        //   786,432 (one plane)
  const size_t S_xdbl = (size_t)Kk*38*Ll;      //   622,592
  const size_t S_h    = (size_t)Kk*NCH*Din*Ns; // 1,572,864
  const size_t S_dts  = (size_t)Kk*NCH*Din;    //    98,304
  const size_t perb   = 7*P1 + S_xdbl + S_h + S_dts;  // 7,798,784 floats = 31.2 MB

  int G = 4;
  if (ws_size < 4*perb*sizeof(float)) G = 2;
  if (ws_size < 2*perb*sizeof(float)) G = 1;
  if (ws_size < 1*perb*sizeof(float)){
    k_sentinel<<<(out_size + 255)/256, 256, 0, stream>>>(out, out_size);
    return;
  }

  float* wsf = (float*)d_ws;
  for (int b0 = 0; b0 < Bn; b0 += G){
    int nb = (Bn - b0 < G) ? (Bn - b0) : G;
    size_t nbP = (size_t)nb*P1;
    float* zbuf  = wsf;                 // [nbP]  plane 0   (cat overlays planes 0-2)
    float* y0    = zbuf + nbP;          // [nbP]  plane 1
    float* y1    = y0   + nbP;          // [nbP]  plane 2
    float* y2p   = y1   + nbP;          // [nbP]  plane 3
    float* y3    = y2p  + nbP;          // [nbP]  plane 4
    float* xi    = y3   + nbP;          // [nbP]  plane 5 (xi_pre -> xi in place; later gbuf)
    float* xiT   = xi   + nbP;          // [nbP]  plane 6
    float* xdbl  = xiT  + nbP;          // [nb*S_xdbl]
    float* hbuf  = xdbl + (size_t)nb*S_xdbl;  // [nb*S_h] (hend -> hin in place)
    float* dtsum = hbuf + (size_t)nb*S_h;     // [nb*S_dts]
    float* cat   = wsf;                 // [3*nbP] == nb*576*Ll exactly (planes 0-2)
    float* gbuf  = xi;

    const float* xg = x + (size_t)b0*Ll*96;
    float* outg = out + (size_t)b0*Ll*96;

    k_inproj <<<dim3(nb*64, 6), 256, 0, stream>>>(xg, ipw, xi, zbuf);
    k_dwconv <<<nb*Din, 256, 0, stream>>>(xi, cw, cb, xiT);
    k_xdbl   <<<nb*128, 256, 0, stream>>>(xi, xiT, xpw, xdbl);
    k_scan1  <<<nb*Kk*NCH, 192, 0, stream>>>(xi, xiT, xdbl, dtw, dtb, Alog, hbuf, dtsum);
    k_combine<<<nb*48, 256, 0, stream>>>(Alog, dtsum, hbuf);
    k_scany  <<<nb*Kk*NCH, 192, 0, stream>>>(xi, xiT, xdbl, dtw, dtb, Alog, Ds, hbuf,
                                             y0, y1, y2p, y3);
    k_merge  <<<nb*Din, 256, 0, stream>>>(y0, y1, y2p, y3);
    k_ln     <<<nb*64, 256, 0, stream>>>(y0, zbuf, ong, onb, gbuf);
    k_branch <<<nb*Din, 256, 0, stream>>>(gbuf, brw, brg, brb, cat);
    k_fuse   <<<nb*64, 512, 0, stream>>>(cat, fw, fg, fb, outg);
  }
}

// Round 19
// 262.919 us; speedup vs baseline: 1.1614x; 1.0025x over previous
//
#include <hip/hip_runtime.h>
#include <hip/hip_bf16.h>
#include <hip/hip_fp16.h>
#include <math.h>

// ---------------- constants (problem-fixed shapes) ----------------
constexpr int Bn  = 4;      // batch
constexpr int Din = 192;    // d_inner
constexpr int Ll  = 4096;   // L = H*W
constexpr int Kk  = 4;      // scan directions
constexpr int Ns  = 16;     // d_state
constexpr int NCH = 128;    // scan chunks
constexpr int CLen= 32;     // chunk length
constexpr float EPSBN = 1e-5f;
constexpr float EPSLN = 1e-5f;

#define DEV __device__ __forceinline__

DEV float siluf_(float x){ return x / (1.f + __expf(-x)); }
DEV float softplusf_(float x){ return x > 15.f ? x : __logf(1.f + __expf(x)); }

// ---------------- K1: in_proj GEMM (nb*4096 x 96 @ 96 x 384^T) + split + silu(z) ----------------
__global__ __launch_bounds__(256) void k_inproj(const float* __restrict__ x,
                                                const float* __restrict__ w,
                                                float* __restrict__ xi_pre,
                                                float* __restrict__ zbuf){
  __shared__ __align__(16) float As[32][72];
  __shared__ __align__(16) float Bs[32][72];
  int t = threadIdx.x, tx = t & 15, ty = t >> 4;
  int m0 = blockIdx.x * 64, o0 = blockIdx.y * 64;
  float acc[4][4] = {};
  for (int k0 = 0; k0 < 96; k0 += 32){
    #pragma unroll
    for (int i = 0; i < 8; i++){ int e = t + i*256; int kk = e & 31, mm = e >> 5;
      As[kk][mm] = x[(size_t)(m0+mm)*96 + k0+kk]; }
    #pragma unroll
    for (int i = 0; i < 8; i++){ int e = t + i*256; int kk = e & 31, nn = e >> 5;
      Bs[kk][nn] = w[(size_t)(o0+nn)*96 + k0+kk]; }
    __syncthreads();
    #pragma unroll
    for (int kk = 0; kk < 32; kk++){
      float a[4], bb[4];
      #pragma unroll
      for (int i = 0; i < 4; i++) a[i]  = As[kk][tx + 16*i];
      #pragma unroll
      for (int j = 0; j < 4; j++) bb[j] = Bs[kk][ty + 16*j];
      #pragma unroll
      for (int i = 0; i < 4; i++)
        #pragma unroll
        for (int j = 0; j < 4; j++) acc[i][j] = fmaf(a[i], bb[j], acc[i][j]);
    }
    __syncthreads();
  }
  #pragma unroll
  for (int i = 0; i < 4; i++){
    int m = m0 + tx + 16*i; int b = m >> 12, l = m & 4095;
    #pragma unroll
    for (int j = 0; j < 4; j++){
      int o = o0 + ty + 16*j; float v = acc[i][j];
      if (o < Din) xi_pre[((size_t)b*Din + o)*Ll + l] = v;
      else         zbuf[((size_t)b*Din + (o-Din))*Ll + l] = siluf_(v);
    }
  }
}

// ---------------- K2: depthwise 3x3 conv + bias + silu; IN-PLACE xi, also emits xiT ----------------
__global__ __launch_bounds__(256) void k_dwconv(float* __restrict__ xi,
                                                const float* __restrict__ cw,
                                                const float* __restrict__ cb,
                                                float* __restrict__ xiT){
  __shared__ float pl[64][65];
  __shared__ float po[64][65];
  int g = blockIdx.x; int d = g % Din;
  int t = threadIdx.x;
  float* plane = xi + (size_t)g*Ll;
  #pragma unroll
  for (int i = 0; i < 16; i++){ int p = t + i*256; pl[p>>6][p&63] = plane[p]; }
  float w9[9];
  #pragma unroll
  for (int j = 0; j < 9; j++) w9[j] = cw[d*9 + j];
  float bias = cb[d];
  __syncthreads();
  float out[16];
  #pragma unroll
  for (int i = 0; i < 16; i++){
    int p = t + i*256; int h = p >> 6, wv = p & 63;
    float s = bias;
    #pragma unroll
    for (int r = 0; r < 3; r++){
      int hy = h + r - 1; if (hy < 0 || hy > 63) continue;
      #pragma unroll
      for (int c = 0; c < 3; c++){
        int wx = wv + c - 1; if (wx < 0 || wx > 63) continue;
        s = fmaf(pl[hy][wx], w9[r*3+c], s);
      }
    }
    out[i] = siluf_(s);
  }
  __syncthreads();
  #pragma unroll
  for (int i = 0; i < 16; i++){ int p = t + i*256; po[p>>6][p&63] = out[i]; plane[p] = out[i]; }
  __syncthreads();
  float* dxt = xiT + (size_t)g*Ll;
  #pragma unroll
  for (int i = 0; i < 16; i++){ int p = t + i*256; dxt[p] = po[p&63][p>>6]; }
}

// ---------------- K3: x_dbl = einsum('bkdl,kcd->bkcl') — r12 shape + register prefetch ----------------
__global__ __launch_bounds__(256) void k_xdbl(const float* __restrict__ xi,
                                              const float* __restrict__ xiT,
                                              const float* __restrict__ xpw,
                                              float* __restrict__ xdbl){
  __shared__ float us[24][132];
  __shared__ __align__(16) float wl[24][40];
  int g = blockIdx.x; int b = g >> 7; int k = (g >> 5) & 3; int lt = g & 31;
  int l0 = lt * 128; int t = threadIdx.x;
  int lw = t & 127; int cg = t >> 7;          // c-group 0/1 (c = cg*20 .. +19)
  const float* src = (k & 1) ? xiT : xi;
  bool rev = (k >= 2);
  if (t < 48){ wl[t >> 1][38 + (t & 1)] = 0.f; }   // pad cols, written once
  float acc[20];
  #pragma unroll
  for (int j = 0; j < 20; j++) acc[j] = 0.f;
  float upf[12]; float wpf[4];
  // prefetch chunk 0
  #pragma unroll
  for (int i = 0; i < 12; i++){ int e = t + i*256; int dd = e >> 7, ll = e & 127;
    int sp = rev ? (4095 - (l0 + ll)) : (l0 + ll);
    upf[i] = src[((size_t)b*Din + dd)*Ll + sp]; }
  #pragma unroll
  for (int i = 0; i < 4; i++){ int e = t + i*256;
    if (e < 912){ int dd = e % 24, c = e / 24; wpf[i] = xpw[(k*38 + c)*Din + dd]; } }
  for (int dc = 0; dc < 8; dc++){
    #pragma unroll
    for (int i = 0; i < 12; i++){ int e = t + i*256; us[e >> 7][e & 127] = upf[i]; }
    #pragma unroll
    for (int i = 0; i < 4; i++){ int e = t + i*256;
      if (e < 912){ wl[e % 24][e / 24] = wpf[i]; } }
    __syncthreads();
    if (dc < 7){
      int d0n = (dc + 1) * 24;
      #pragma unroll
      for (int i = 0; i < 12; i++){ int e = t + i*256; int dd = e >> 7, ll = e & 127;
        int sp = rev ? (4095 - (l0 + ll)) : (l0 + ll);
        upf[i] = src[((size_t)b*Din + d0n + dd)*Ll + sp]; }
      #pragma unroll
      for (int i = 0; i < 4; i++){ int e = t + i*256;
        if (e < 912){ int dd = e % 24, c = e / 24; wpf[i] = xpw[(k*38 + c)*Din + d0n + dd]; } }
    }
    #pragma unroll
    for (int dd = 0; dd < 24; dd++){
      float u = us[dd][lw];
      const float4* wp = (const float4*)&wl[dd][cg*20];
      #pragma unroll
      for (int q = 0; q < 5; q++){
        float4 w4 = wp[q];
        acc[q*4+0] = fmaf(u, w4.x, acc[q*4+0]);
        acc[q*4+1] = fmaf(u, w4.y, acc[q*4+1]);
        acc[q*4+2] = fmaf(u, w4.z, acc[q*4+2]);
        acc[q*4+3] = fmaf(u, w4.w, acc[q*4+3]);
      }
    }
    __syncthreads();
  }
  float* dst = xdbl + ((size_t)(b*Kk + k)*38)*Ll + l0 + lw;
  #pragma unroll
  for (int j = 0; j < 20; j++){
    int c = cg*20 + j;
    if (c < 38) dst[(size_t)c*Ll] = acc[j];
  }
}

// ---------------- K4: scan pass 1 — fp16 u-stage (LDS 16KB -> higher occupancy) ----------------
__global__ __launch_bounds__(192) void k_scan1(const float* __restrict__ xi,
                                               const float* __restrict__ xiT,
                                               const float* __restrict__ xdbl,
                                               const float* __restrict__ dtw_g,
                                               const float* __restrict__ dtb_g,
                                               const float* __restrict__ Alog,
                                               float* __restrict__ hend,
                                               float* __restrict__ dtsum){
  __shared__ __align__(16) float bc[CLen][16];
  __shared__ __align__(16) float dr[CLen][8];
  __shared__ __half us[192][34];
  int g = blockIdx.x;
  int b = g / (Kk*NCH); int k = (g / NCH) & 3; int ch = g % NCH;
  int l0 = ch * CLen;
  int t = threadIdx.x;             // t = d (0..191)
  const float* xb = xdbl + ((size_t)(b*Kk + k)*38)*Ll;
  for (int e = t; e < CLen*16; e += 192){ int n = e / CLen, ll = e % CLen;
    bc[ll][n] = xb[(6 + n)*Ll + l0 + ll]; }
  for (int e = t; e < CLen*6; e += 192){ int r = e / CLen, ll = e % CLen;
    dr[ll][r] = xb[r*Ll + l0 + ll]; }
  const float* ubase = ((k & 1) ? xiT : xi) + (size_t)b*Din*Ll;
  bool rev = (k >= 2);
  for (int e = t; e < 192*CLen; e += 192){
    int dd = e >> 5, ll = e & 31;
    int sp = rev ? (Ll-1 - l0 - ll) : (l0 + ll);
    us[dd][ll] = __float2half(ubase[(size_t)dd*Ll + sp]);
  }
  int d = t; int kd = k*Din + d;
  float dtw[6];
  #pragma unroll
  for (int r = 0; r < 6; r++) dtw[r] = dtw_g[kd*6 + r];
  float dtb = dtb_g[kd];
  float Ar[16];
  #pragma unroll
  for (int n = 0; n < 16; n++) Ar[n] = -__expf(Alog[kd*16 + n]);
  bool ok = true;
  #pragma unroll
  for (int n = 1; n < 16; n++)
    ok = ok && (fabsf(Ar[n] - (n+1)*Ar[0]) <= 1e-4f*fabsf(Ar[n]) + 1e-30f);
  float h[16];
  #pragma unroll
  for (int n = 0; n < 16; n++) h[n] = 0.f;
  float dts_acc = 0.f;
  __syncthreads();
  if (ok){
    for (int ll = 0; ll < CLen; ll++){
      float4 q0 = *(const float4*)&dr[ll][0];
      float4 q1 = *(const float4*)&dr[ll][4];
      float xv = dtb;
      xv = fmaf(dtw[0], q0.x, xv); xv = fmaf(dtw[1], q0.y, xv); xv = fmaf(dtw[2], q0.z, xv);
      xv = fmaf(dtw[3], q0.w, xv); xv = fmaf(dtw[4], q1.x, xv); xv = fmaf(dtw[5], q1.y, xv);
      float dt = softplusf_(xv);
      float u = __half2float(us[d][ll]);
      float dtu = dt * u;
      float e1 = __expf(dt * Ar[0]);
      float e2=e1*e1, e4=e2*e2, e8=e4*e4;
      float dA[16];
      dA[0]=e1; dA[1]=e2; dA[2]=e2*e1; dA[3]=e4; dA[4]=e4*e1; dA[5]=e4*e2; dA[6]=e4*e2*e1;
      dA[7]=e8; dA[8]=e8*e1; dA[9]=e8*e2; dA[10]=e8*e2*e1; dA[11]=e8*e4; dA[12]=e8*e4*e1;
      dA[13]=e8*e4*e2; dA[14]=e8*e4*e2*e1; dA[15]=e8*e8;
      float4 B0 = *(const float4*)&bc[ll][0];
      float4 B1 = *(const float4*)&bc[ll][4];
      float4 B2 = *(const float4*)&bc[ll][8];
      float4 B3 = *(const float4*)&bc[ll][12];
      float Bv[16] = {B0.x,B0.y,B0.z,B0.w,B1.x,B1.y,B1.z,B1.w,
                      B2.x,B2.y,B2.z,B2.w,B3.x,B3.y,B3.z,B3.w};
      #pragma unroll
      for (int n = 0; n < 16; n++) h[n] = fmaf(h[n], dA[n], dtu * Bv[n]);
      dts_acc += dt;
    }
  } else {
    for (int ll = 0; ll < CLen; ll++){
      float4 q0 = *(const float4*)&dr[ll][0];
      float4 q1 = *(const float4*)&dr[ll][4];
      float xv = dtb;
      xv = fmaf(dtw[0], q0.x, xv); xv = fmaf(dtw[1], q0.y, xv); xv = fmaf(dtw[2], q0.z, xv);
      xv = fmaf(dtw[3], q0.w, xv); xv = fmaf(dtw[4], q1.x, xv); xv = fmaf(dtw[5], q1.y, xv);
      float dt = softplusf_(xv);
      float u = __half2float(us[d][ll]);
      float dtu = dt * u;
      float4 B0 = *(const float4*)&bc[ll][0];
      float4 B1 = *(const float4*)&bc[ll][4];
      float4 B2 = *(const float4*)&bc[ll][8];
      float4 B3 = *(const float4*)&bc[ll][12];
      float Bv[16] = {B0.x,B0.y,B0.z,B0.w,B1.x,B1.y,B1.z,B1.w,
                      B2.x,B2.y,B2.z,B2.w,B3.x,B3.y,B3.z,B3.w};
      #pragma unroll
      for (int n = 0; n < 16; n++){
        float dA = __expf(dt * Ar[n]);
        h[n] = fmaf(h[n], dA, dtu * Bv[n]);
      }
      dts_acc += dt;
    }
  }
  float4* hp = (float4*)&hend[(((size_t)(b*Kk + k)*NCH + ch)*Din + d)*16];
  #pragma unroll
  for (int q = 0; q < 4; q++){
    float4 v; v.x = h[q*4]; v.y = h[q*4+1]; v.z = h[q*4+2]; v.w = h[q*4+3];
    hp[q] = v;
  }
  dtsum[((size_t)(b*Kk + k)*NCH + ch)*Din + d] = dts_acc;
}

// ---------------- K5: serial combine across chunks, IN-PLACE hend -> hin ----------------
__global__ __launch_bounds__(256) void k_combine(const float* __restrict__ Alog,
                                                 const float* __restrict__ dtsum,
                                                 float* __restrict__ hbuf){
  __shared__ float ds_s[NCH][17];
  int blk = blockIdx.x;
  int bk = blk / 12; int d0 = (blk % 12) * 16;   // Din*Ns/256 = 12
  int k = bk & 3;
  int t = threadIdx.x; int n = t & 15; int dd = t >> 4;  // dd 0..15
  int d = d0 + dd;
  for (int e = t; e < NCH*16; e += 256){ int c = e >> 4, di = e & 15;
    ds_s[c][di] = dtsum[(size_t)bk*NCH*Din + (size_t)c*Din + d0 + di]; }
  float A = -__expf(Alog[(k*Din + d)*16 + n]);
  __syncthreads();
  float h = 0.f;
  size_t base = ((size_t)bk*NCH*Din + d)*16 + n;       // + c*Din*16
  #pragma unroll 4
  for (int c = 0; c < NCH; c++){
    size_t idx = base + (size_t)c*(Din*16);
    float tmp = hbuf[idx];
    hbuf[idx] = h;                                     // prefix state (hin)
    h = fmaf(h, __expf(A * ds_s[c][dd]), tmp);
  }
}

// ---------------- K6: scan pass 2 — fp16 u/y LDS stage; coalesced store ----------------
__global__ __launch_bounds__(192) void k_scany(const float* __restrict__ xi,
                                               const float* __restrict__ xiT,
                                               const float* __restrict__ xdbl,
                                               const float* __restrict__ dtw_g,
                                               const float* __restrict__ dtb_g,
                                               const float* __restrict__ Alog,
                                               const float* __restrict__ Ds_g,
                                               const float* __restrict__ hin,
                                               float* __restrict__ y0,
                                               float* __restrict__ y1,
                                               float* __restrict__ y2p,
                                               float* __restrict__ y3){
  // bc layout per ll: [0..15]=B, [16..31]=C, [32..37]=dt-raw (38,39 pad)
  __shared__ __align__(16) float bc[CLen][40];
  __shared__ __half us[192][34];         // u on input; y on output (slot reused per step)
  int g = blockIdx.x;
  int b = g / (Kk*NCH); int k = (g / NCH) & 3; int ch = g % NCH;
  int l0 = ch * CLen; int t = threadIdx.x;
  const float* xb = xdbl + ((size_t)(b*Kk + k)*38)*Ll;
  for (int e = t; e < CLen*38; e += 192){
    int c = e / CLen, ll = e % CLen;
    int cp = (c < 6) ? (32 + c) : (c - 6);
    bc[ll][cp] = xb[c*Ll + l0 + ll];
  }
  const float* ubase = ((k & 1) ? xiT : xi) + (size_t)b*Din*Ll;
  bool rev = (k >= 2);
  for (int e = t; e < 192*CLen; e += 192){
    int dd = e >> 5, ll = e & 31;
    int sp = rev ? (Ll-1 - l0 - ll) : (l0 + ll);
    us[dd][ll] = __float2half(ubase[(size_t)dd*Ll + sp]);
  }
  int d = t; int kd = k*Din + d;
  float dtw[6];
  #pragma unroll
  for (int r = 0; r < 6; r++) dtw[r] = dtw_g[kd*6 + r];
  float dtb = dtb_g[kd];
  float Ar[16];
  #pragma unroll
  for (int n = 0; n < 16; n++) Ar[n] = -__expf(Alog[kd*16 + n]);
  bool ok = true;
  #pragma unroll
  for (int n = 1; n < 16; n++)
    ok = ok && (fabsf(Ar[n] - (n+1)*Ar[0]) <= 1e-4f*fabsf(Ar[n]) + 1e-30f);
  float Dk = Ds_g[kd];
  float h[16];
  {
    const float4* hp = (const float4*)&hin[(((size_t)(b*Kk + k)*NCH + ch)*Din + d)*16];
    #pragma unroll
    for (int q = 0; q < 4; q++){ float4 v = hp[q];
      h[q*4] = v.x; h[q*4+1] = v.y; h[q*4+2] = v.z; h[q*4+3] = v.w; }
  }
  __syncthreads();
  if (ok){
    for (int ll = 0; ll < CLen; ll++){
      float4 q0 = *(const float4*)&bc[ll][32];
      float4 q1 = *(const float4*)&bc[ll][36];
      float xv = dtb;
      xv = fmaf(dtw[0], q0.x, xv); xv = fmaf(dtw[1], q0.y, xv); xv = fmaf(dtw[2], q0.z, xv);
      xv = fmaf(dtw[3], q0.w, xv); xv = fmaf(dtw[4], q1.x, xv); xv = fmaf(dtw[5], q1.y, xv);
      float dt = softplusf_(xv);
      float u = __half2float(us[d][ll]);
      float dtu = dt * u;
      float e1 = __expf(dt * Ar[0]);
      float e2=e1*e1, e4=e2*e2, e8=e4*e4;
      float dA[16];
      dA[0]=e1; dA[1]=e2; dA[2]=e2*e1; dA[3]=e4; dA[4]=e4*e1; dA[5]=e4*e2; dA[6]=e4*e2*e1;
      dA[7]=e8; dA[8]=e8*e1; dA[9]=e8*e2; dA[10]=e8*e2*e1; dA[11]=e8*e4; dA[12]=e8*e4*e1;
      dA[13]=e8*e4*e2; dA[14]=e8*e4*e2*e1; dA[15]=e8*e8;
      float4 B0 = *(const float4*)&bc[ll][0];
      float4 B1 = *(const float4*)&bc[ll][4];
      float4 B2 = *(const float4*)&bc[ll][8];
      float4 B3 = *(const float4*)&bc[ll][12];
      float Bv[16] = {B0.x,B0.y,B0.z,B0.w,B1.x,B1.y,B1.z,B1.w,
                      B2.x,B2.y,B2.z,B2.w,B3.x,B3.y,B3.z,B3.w};
      #pragma unroll
      for (int n = 0; n < 16; n++) h[n] = fmaf(h[n], dA[n], dtu * Bv[n]);
      float4 C0 = *(const float4*)&bc[ll][16];
      float4 C1 = *(const float4*)&bc[ll][20];
      float4 C2 = *(const float4*)&bc[ll][24];
      float4 C3 = *(const float4*)&bc[ll][28];
      float Cv[16] = {C0.x,C0.y,C0.z,C0.w,C1.x,C1.y,C1.z,C1.w,
                      C2.x,C2.y,C2.z,C2.w,C3.x,C3.y,C3.z,C3.w};
      float y = 0.f;
      #pragma unroll
      for (int n = 0; n < 16; n++) y = fmaf(h[n], Cv[n], y);
      y = fmaf(Dk, u, y);
      us[d][ll] = __float2half(y);        // reuse LDS slot (u consumed this step)
    }
  } else {
    for (int ll = 0; ll < CLen; ll++){
      float4 q0 = *(const float4*)&bc[ll][32];
      float4 q1 = *(const float4*)&bc[ll][36];
      float xv = dtb;
      xv = fmaf(dtw[0], q0.x, xv); xv = fmaf(dtw[1], q0.y, xv); xv = fmaf(dtw[2], q0.z, xv);
      xv = fmaf(dtw[3], q0.w, xv); xv = fmaf(dtw[4], q1.x, xv); xv = fmaf(dtw[5], q1.y, xv);
      float dt = softplusf_(xv);
      float u = __half2float(us[d][ll]);
      float dtu = dt * u;
      float4 B0 = *(const float4*)&bc[ll][0];
      float4 B1 = *(const float4*)&bc[ll][4];
      float4 B2 = *(const float4*)&bc[ll][8];
      float4 B3 = *(const float4*)&bc[ll][12];
      float Bv[16] = {B0.x,B0.y,B0.z,B0.w,B1.x,B1.y,B1.z,B1.w,
                      B2.x,B2.y,B2.z,B2.w,B3.x,B3.y,B3.z,B3.w};
      #pragma unroll
      for (int n = 0; n < 16; n++){
        float dA = __expf(dt * Ar[n]);
        h[n] = fmaf(h[n], dA, dtu * Bv[n]);
      }
      float4 C0 = *(const float4*)&bc[ll][16];
      float4 C1 = *(const float4*)&bc[ll][20];
      float4 C2 = *(const float4*)&bc[ll][24];
      float4 C3 = *(const float4*)&bc[ll][28];
      float Cv[16] = {C0.x,C0.y,C0.z,C0.w,C1.x,C1.y,C1.z,C1.w,
                      C2.x,C2.y,C2.z,C2.w,C3.x,C3.y,C3.z,C3.w};
      float y = 0.f;
      #pragma unroll
      for (int n = 0; n < 16; n++) y = fmaf(h[n], Cv[n], y);
      y = fmaf(Dk, u, y);
      us[d][ll] = __float2half(y);
    }
  }
  __syncthreads();
  // coalesced write-out: mirrors the staging loop (32-lane groups, 128B contiguous)
  float* yplane = (k == 0 ? y0 : k == 1 ? y1 : k == 2 ? y2p : y3) + (size_t)b*Din*Ll;
  for (int e = t; e < 192*CLen; e += 192){
    int dd = e >> 5, ll = e & 31;
    int sp = rev ? (Ll-1 - l0 - ll) : (l0 + ll);
    yplane[(size_t)dd*Ll + sp] = __half2float(us[dd][ll]);
  }
}

// ---------------- K7: merge y0 += y2p + T(y1 + y3), in place ----------------
__global__ __launch_bounds__(256) void k_merge(float* __restrict__ y0,
                                               const float* __restrict__ y1,
                                               const float* __restrict__ y2p,
                                               const float* __restrict__ y3){
  __shared__ float pl[64][65];
  int g = blockIdx.x;
  int t = threadIdx.x;
  const float* s1 = y1 + (size_t)g*Ll;
  const float* s3 = y3 + (size_t)g*Ll;
  const float* s2 = y2p + (size_t)g*Ll;
  float* dst = y0 + (size_t)g*Ll;
  #pragma unroll
  for (int i = 0; i < 16; i++){ int p = t + i*256; pl[p>>6][p&63] = s1[p] + s3[p]; }
  __syncthreads();
  #pragma unroll
  for (int i = 0; i < 16; i++){ int p = t + i*256; dst[p] += s2[p] + pl[p&63][p>>6]; }
}

// ---------------- K8: channel LayerNorm + gate (y * silu_z) ----------------
__global__ __launch_bounds__(256) void k_ln(const float* __restrict__ ycf,
                                            const float* __restrict__ zbuf,
                                            const float* __restrict__ gam,
                                            const float* __restrict__ bet,
                                            float* __restrict__ gbuf){
  __shared__ float sred[2][4][64];
  __shared__ float smu[64], srs[64];
  int g = blockIdx.x; int b = g >> 6; int l0 = (g & 63) * 64;
  int t = threadIdx.x; int lw = t & 63; int dg = t >> 6;
  size_t pbase = ((size_t)b*Din + dg*48)*Ll + l0 + lw;
  float sum = 0.f, ss = 0.f;
  for (int dd = 0; dd < 48; dd++){
    float v = ycf[pbase + (size_t)dd*Ll]; sum += v; ss = fmaf(v, v, ss);
  }
  sred[0][dg][lw] = sum; sred[1][dg][lw] = ss;
  __syncthreads();
  if (t < 64){
    float s = sred[0][0][t] + sred[0][1][t] + sred[0][2][t] + sred[0][3][t];
    float q = sred[1][0][t] + sred[1][1][t] + sred[1][2][t] + sred[1][3][t];
    float mu = s * (1.f/192.f);
    float var = q * (1.f/192.f) - mu*mu;
    smu[t] = mu; srs[t] = rsqrtf(var + EPSLN);
  }
  __syncthreads();
  float mu = smu[lw], rs = srs[lw];
  for (int dd = 0; dd < 48; dd++){
    int d = dg*48 + dd;
    float v = ycf[pbase + (size_t)dd*Ll];
    float vn = (v - mu)*rs*gam[d] + bet[d];
    float zz = zbuf[((size_t)b*Din + d)*Ll + l0 + lw];
    gbuf[((size_t)b*Din + d)*Ll + l0 + lw] = vn * zz;
  }
}

// ---------------- K9: 3 dilated depthwise convs + BN + ReLU -> cat ----------------
__global__ __launch_bounds__(256) void k_branch(const float* __restrict__ gbuf,
                                                const float* __restrict__ brw,
                                                const float* __restrict__ brg,
                                                const float* __restrict__ brb,
                                                float* __restrict__ cat){
  __shared__ float pl[64][65];
  int g = blockIdx.x; int b = g / Din, d = g % Din;
  int t = threadIdx.x;
  const float* src = gbuf + (size_t)g*Ll;
  #pragma unroll
  for (int i = 0; i < 16; i++){ int p = t + i*256; pl[p>>6][p&63] = src[p]; }
  float w[3][9]; float sc[3], bi[3];
  const float inv = rsqrtf(1.f + EPSBN);
  #pragma unroll
  for (int ib = 0; ib < 3; ib++){
    #pragma unroll
    for (int j = 0; j < 9; j++) w[ib][j] = brw[(ib*Din + d)*9 + j];
    sc[ib] = brg[ib*Din + d] * inv; bi[ib] = brb[ib*Din + d];
  }
  __syncthreads();
  const int dils[3] = {1, 2, 4};
  #pragma unroll
  for (int i = 0; i < 16; i++){
    int p = t + i*256; int h = p >> 6, wv = p & 63;
    #pragma unroll
    for (int ib = 0; ib < 3; ib++){
      int dil = dils[ib];
      float s = 0.f;
      #pragma unroll
      for (int r = 0; r < 3; r++){
        int hy = h + (r-1)*dil; if (hy < 0 || hy > 63) continue;
        #pragma unroll
        for (int c = 0; c < 3; c++){
          int wx = wv + (c-1)*dil; if (wx < 0 || wx > 63) continue;
          s = fmaf(pl[hy][wx], w[ib][r*3+c], s);
        }
      }
      s = s*sc[ib] + bi[ib];
      s = s > 0.f ? s : 0.f;
      cat[((size_t)b*576 + ib*Din + d)*Ll + p] = s;
    }
  }
}

// ---------------- K10: fuse 1x1 GEMM, M=64 N=96 K=32, 512 threads; float2 A-reads + reg prefetch ----------------
__global__ __launch_bounds__(512) void k_fuse(const float* __restrict__ cat,
                                              const float* __restrict__ fw,
                                              const float* __restrict__ fg,
                                              const float* __restrict__ fb,
                                              float* __restrict__ out){
  __shared__ __align__(16) float As[32][66];   // [k][m]  row stride 264B (8B-aligned), 66 mod 32 = 2
  __shared__ float Bs[32][97];                 // [k][n]  odd stride -> conflict-free
  int t = threadIdx.x;
  int tx = t & 31, ty = t >> 5;                // tx -> n (0..31), ty -> m-pair (0..15)
  int m0 = blockIdx.x * 64; int b = m0 >> 12; int l0 = m0 & 4095;
  float acc[4][3] = {};
  float apf[4], bpf[6];
  // prefetch K-tile 0
  #pragma unroll
  for (int i = 0; i < 4; i++){ int e = t + i*512; int mm = e & 63, kk = e >> 6;
    apf[i] = cat[((size_t)b*576 + kk)*Ll + l0 + mm]; }
  #pragma unroll
  for (int i = 0; i < 6; i++){ int e = t + i*512; int kk = e & 31, oo = e >> 5;
    bpf[i] = fw[(size_t)oo*576 + kk]; }
  for (int k0 = 0; k0 < 576; k0 += 32){
    // write prefetched tile into LDS
    #pragma unroll
    for (int i = 0; i < 4; i++){ int e = t + i*512; As[e >> 6][e & 63] = apf[i]; }
    #pragma unroll
    for (int i = 0; i < 6; i++){ int e = t + i*512; Bs[e & 31][e >> 5] = bpf[i]; }
    __syncthreads();
    if (k0 < 544){
      int k0n = k0 + 32;
      #pragma unroll
      for (int i = 0; i < 4; i++){ int e = t + i*512; int mm = e & 63, kk = e >> 6;
        apf[i] = cat[((size_t)b*576 + k0n + kk)*Ll + l0 + mm]; }
      #pragma unroll
      for (int i = 0; i < 6; i++){ int e = t + i*512; int kk = e & 31, oo = e >> 5;
        bpf[i] = fw[(size_t)oo*576 + k0n + kk]; }
    }
    #pragma unroll
    for (int kk = 0; kk < 32; kk++){
      float2 a01 = *(const float2*)&As[kk][ty*2];        // m = ty*2, ty*2+1
      float2 a23 = *(const float2*)&As[kk][ty*2 + 32];   // m = ty*2+32, ty*2+33
      float a[4] = {a01.x, a01.y, a23.x, a23.y};
      float bb[3];
      #pragma unroll
      for (int j = 0; j < 3; j++) bb[j] = Bs[kk][tx + 32*j];
      #pragma unroll
      for (int i = 0; i < 4; i++)
        #pragma unroll
        for (int j = 0; j < 3; j++) acc[i][j] = fmaf(a[i], bb[j], acc[i][j]);
    }
    __syncthreads();
  }
  const float inv = rsqrtf(1.f + EPSBN);
  const int moff[4] = {0, 1, 32, 33};
  #pragma unroll
  for (int j = 0; j < 3; j++){
    int o = tx + 32*j;
    float sc = fg[o]*inv, bi = fb[o];
    #pragma unroll
    for (int i = 0; i < 4; i++){
      int m = m0 + ty*2 + moff[i];
      float v = acc[i][j]*sc + bi;
      v = v > 0.f ? v : 0.f;
      out[(size_t)m*96 + o] = v;
    }
  }
}

// ---------------- diagnostic sentinel: ws too small even for G=1 ----------------
__global__ void k_sentinel(float* out, int n){
  int i = blockIdx.x*256 + threadIdx.x;
  if (i < n) out[i] = 1.5f;
}

// ---------------- launch ----------------
extern "C" void kernel_launch(void* const* d_in, const int* in_sizes, int n_in,
                              void* d_out, int out_size, void* d_ws, size_t ws_size,
                              hipStream_t stream){
  const float* x    = (const float*)d_in[0];
  const float* ipw  = (const float*)d_in[1];
  const float* cw   = (const float*)d_in[2];
  const float* cb   = (const float*)d_in[3];
  const float* xpw  = (const float*)d_in[4];
  const float* dtw  = (const float*)d_in[5];
  const float* dtb  = (const float*)d_in[6];
  const float* Alog = (const float*)d_in[7];
  const float* Ds   = (const float*)d_in[8];
  const float* ong  = (const float*)d_in[9];
  const float* onb  = (const float*)d_in[10];
  const float* brw  = (const float*)d_in[11];
  const float* brg  = (const float*)d_in[12];
  const float* brb  = (const float*)d_in[13];
  const float* fw   = (const float*)d_in[14];
  const float* fg   = (const float*)d_in[15];
  const float* fb   = (const float*)d_in[16];
  float* out = (float*)d_out;          // reference output dtype = float32

  // per-batch float counts
  const size_t P1     = (size_t)Din*Ll;        //   786,432 (one plane)
  const size_t S_xdbl = (size_t)Kk*38*Ll;      //   622,592
  const size_t S_h    = (size_t)Kk*NCH*Din*Ns; // 1,572,864
  const size_t S_dts  = (size_t)Kk*NCH*Din;    //    98,304
  const size_t perb   = 7*P1 + S_xdbl + S_h + S_dts;  // 7,798,784 floats = 31.2 MB

  int G = 4;
  if (ws_size < 4*perb*sizeof(float)) G = 2;
  if (ws_size < 2*perb*sizeof(float)) G = 1;
  if (ws_size < 1*perb*sizeof(float)){
    k_sentinel<<<(out_size + 255)/256, 256, 0, stream>>>(out, out_size);
    return;
  }

  float* wsf = (float*)d_ws;
  for (int b0 = 0; b0 < Bn; b0 += G){
    int nb = (Bn - b0 < G) ? (Bn - b0) : G;
    size_t nbP = (size_t)nb*P1;
    float* zbuf  = wsf;                 // [nbP]  plane 0   (cat overlays planes 0-2)
    float* y0    = zbuf + nbP;          // [nbP]  plane 1
    float* y1    = y0   + nbP;          // [nbP]  plane 2
    float* y2p   = y1   + nbP;          // [nbP]  plane 3
    float* y3    = y2p  + nbP;          // [nbP]  plane 4
    float* xi    = y3   + nbP;          // [nbP]  plane 5 (xi_pre -> xi in place; later gbuf)
    float* xiT   = xi   + nbP;          // [nbP]  plane 6
    float* xdbl  = xiT  + nbP;          // [nb*S_xdbl]
    float* hbuf  = xdbl + (size_t)nb*S_xdbl;  // [nb*S_h] (hend -> hin in place)
    float* dtsum = hbuf + (size_t)nb*S_h;     // [nb*S_dts]
    float* cat   = wsf;                 // [3*nbP] == nb*576*Ll exactly (planes 0-2)
    float* gbuf  = xi;

    const float* xg = x + (size_t)b0*Ll*96;
    float* outg = out + (size_t)b0*Ll*96;

    k_inproj <<<dim3(nb*64, 6), 256, 0, stream>>>(xg, ipw, xi, zbuf);
    k_dwconv <<<nb*Din, 256, 0, stream>>>(xi, cw, cb, xiT);
    k_xdbl   <<<nb*128, 256, 0, stream>>>(xi, xiT, xpw, xdbl);
    k_scan1  <<<nb*Kk*NCH, 192, 0, stream>>>(xi, xiT, xdbl, dtw, dtb, Alog, hbuf, dtsum);
    k_combine<<<nb*48, 256, 0, stream>>>(Alog, dtsum, hbuf);
    k_scany  <<<nb*Kk*NCH, 192, 0, stream>>>(xi, xiT, xdbl, dtw, dtb, Alog, Ds, hbuf,
                                             y0, y1, y2p, y3);
    k_merge  <<<nb*Din, 256, 0, stream>>>(y0, y1, y2p, y3);
    k_ln     <<<nb*64, 256, 0, stream>>>(y0, zbuf, ong, onb, gbuf);
    k_branch <<<nb*Din, 256, 0, stream>>>(gbuf, brw, brg, brb, cat);
    k_fuse   <<<nb*64, 512, 0, stream>>>(cat, fw, fg, fb, outg);
  }
}